// Round 7
// baseline (2242.506 us; speedup 1.0000x reference)
//
#include <hip/hip_runtime.h>
#include <hip/hip_bf16.h>

typedef __attribute__((ext_vector_type(8))) short bf16x8;
typedef __attribute__((ext_vector_type(4))) float f32x4;

__device__ inline ushort f2bf(float f) {
    uint u = __float_as_uint(f);
    u += 0x7fff + ((u >> 16) & 1);
    return (ushort)(u >> 16);
}
__device__ inline float bf2f(ushort h) {
    return __uint_as_float(((uint)h) << 16);
}

__device__ inline void gload16(const void* g, void* lds) {
    __builtin_amdgcn_global_load_lds(
        (const __attribute__((address_space(1))) void*)g,
        (__attribute__((address_space(3))) void*)lds, 16, 0, 0);
}

// ---------------- converts ----------------
__global__ void conv_bf16(const float* __restrict__ in, ushort* __restrict__ out, int n4) {
    int i = blockIdx.x * 256 + threadIdx.x;
    if (i >= n4) return;
    float4 a = ((const float4*)in)[i];
    ushort4 o;
    o.x = f2bf(a.x); o.y = f2bf(a.y); o.z = f2bf(a.z); o.w = f2bf(a.w);
    ((ushort4*)out)[i] = o;
}

// in: fp32 [K,N] -> out: bf16 [N,K]
__global__ void wconv_t(const float* __restrict__ in, ushort* __restrict__ out, int K, int N) {
    __shared__ float tile[32][33];
    int kb = blockIdx.y * 32, nb = blockIdx.x * 32;
    int tx = threadIdx.x & 31, ty = threadIdx.x >> 5;  // 32 x 8
#pragma unroll
    for (int i = 0; i < 4; i++)
        tile[ty + i * 8][tx] = in[(size_t)(kb + ty + i * 8) * N + nb + tx];
    __syncthreads();
#pragma unroll
    for (int i = 0; i < 4; i++) {
        int n = nb + ty + i * 8, k = kb + tx;
        out[(size_t)n * K + k] = f2bf(tile[tx][ty + i * 8]);
    }
}

__global__ void biascat(const float* __restrict__ a, const float* __restrict__ b,
                        const float* __restrict__ c, float* __restrict__ o) {
    int i = blockIdx.x * 256 + threadIdx.x;
    if (i < 512) o[i] = a[i];
    else if (i < 1024) o[i] = b[i - 512];
    else if (i < 1536) o[i] = c[i - 1024];
}

// ============ 256x256 GEMM, 2 blocks/CU: C = A[M,K] @ Bt[N,K]^T + bias ============
// 512 threads (8 waves, 2Mx4N), BK=32, 2-buffer LDS rotation (64 KB dynamic) so TWO
// blocks co-reside per CU (__launch_bounds__(512,4)): one block's MFMA phases cover
// the other's prologue/epilogue/stage stalls -- the round-6 bottleneck (1 block/CU,
// Kt=16, serial prologue+epilogue ~40% of block life).
// Race safety (2-buffer):
//  - STAGE(kt+1) at tile-kt top writes buf[(kt+1)&1]==buf[(kt-1)&1]; every wave
//    drained lgkmcnt(0) on its buf[kt-1] reads BEFORE tile kt-1's END barrier,
//    which precedes this STAGE. No write-after-read race.
//  - vmcnt(4) at top: stage(kt) fully landed (stage(kt+1)'s 4 loads remain in
//    flight); top barrier makes it visible to all waves before any ds_read.
//  - END barrier each tile: all waves' reads of buf[kt&1] complete before the
//    next iteration's STAGE targets it.
// EPI: 2 = relu bf16; 3 = bf16 residual add; 4 = fused QKV (seg<2: elu+1) -> [3][M][512]
template <int EPI>
__global__ __launch_bounds__(512, 4) void gemm256(
    const ushort* __restrict__ A, const ushort* __restrict__ Bt,
    const float* __restrict__ bias, const ushort* __restrict__ res16,
    ushort* __restrict__ out16, int M, int N, int K, int nbx) {
    extern __shared__ char smem[];  // 2 * 32768
    const int t = threadIdx.x;
    const int w = t >> 6, l = t & 63;
    const int wr = w >> 2, wc = w & 3;
    // XCD-chunked bijective swizzle (grid divisible by 8)
    const int nwg = gridDim.x;
    const int cpx = nwg >> 3;
    const int swz = (blockIdx.x & 7) * cpx + (blockIdx.x >> 3);
    const int bx = swz % nbx, by = swz / nbx;

    // staging source: thread t covers storage bytes t*16 of each 8KB quarter.
    // storage row = t>>2, storage chunk = t&3; source logical chunk = (t&3)^((row>>1)&3)
    const int sc = (t & 3) ^ ((t >> 3) & 3);
    const ushort* gA0 = A + (size_t)(by * 256 + (t >> 2)) * K + sc * 8;
    const ushort* gA1 = gA0 + (size_t)128 * K;
    const ushort* gB0 = Bt + (size_t)(bx * 256 + (t >> 2)) * K + sc * 8;
    const ushort* gB1 = gB0 + (size_t)128 * K;

#define STAGE(kt)                                             \
    {                                                         \
        char* Lb = smem + ((kt) & 1) * 32768 + (w << 10);     \
        const int ko_ = (kt) * 32;                            \
        gload16(gA0 + ko_, Lb);                               \
        gload16(gA1 + ko_, Lb + 8192);                        \
        gload16(gB0 + ko_, Lb + 16384);                       \
        gload16(gB1 + ko_, Lb + 24576);                       \
    }

    f32x4 acc[8][4] = {};
    const int Kt = K >> 5;

    // ds_read offsets (constant per thread): logical (row, kchunk=l>>4) -> swizzled chunk
    const int R0a = wr * 128 + (l & 15);
    const int offA = R0a * 64 + (((l >> 4) ^ ((R0a >> 1) & 3)) << 4);
    const int R0b = wc * 64 + (l & 15);
    const int offB = 16384 + R0b * 64 + (((l >> 4) ^ ((R0b >> 1) & 3)) << 4);

    STAGE(0);

#pragma unroll 1
    for (int kt = 0; kt < Kt; ++kt) {
        if (kt + 1 < Kt) STAGE(kt + 1);
        if (kt + 1 < Kt) asm volatile("s_waitcnt vmcnt(4)" ::: "memory");
        else             asm volatile("s_waitcnt vmcnt(0)" ::: "memory");
        __builtin_amdgcn_s_barrier();          // stage(kt) visible to all waves
        __builtin_amdgcn_sched_barrier(0);

        const char* bufp = smem + (kt & 1) * 32768;
        bf16x8 a[8], b[4];
        // ---- phase 1: issue reads (b0-3, a0-3), stagger barrier, consume
        b[0] = *(const bf16x8*)(bufp + offB);
        b[1] = *(const bf16x8*)(bufp + offB + 1024);
        b[2] = *(const bf16x8*)(bufp + offB + 2048);
        b[3] = *(const bf16x8*)(bufp + offB + 3072);
        a[0] = *(const bf16x8*)(bufp + offA);
        a[1] = *(const bf16x8*)(bufp + offA + 1024);
        a[2] = *(const bf16x8*)(bufp + offA + 2048);
        a[3] = *(const bf16x8*)(bufp + offA + 3072);
        __builtin_amdgcn_sched_barrier(0);
        __builtin_amdgcn_s_barrier();
        asm volatile("s_waitcnt lgkmcnt(0)" ::: "memory");
        __builtin_amdgcn_sched_barrier(0);
        __builtin_amdgcn_s_setprio(1);
#pragma unroll
        for (int m = 0; m < 4; m++)
#pragma unroll
            for (int n = 0; n < 4; n++)
                acc[m][n] = __builtin_amdgcn_mfma_f32_16x16x32_bf16(a[m], b[n], acc[m][n], 0, 0, 0);
        __builtin_amdgcn_s_setprio(0);
        __builtin_amdgcn_sched_barrier(0);
        // ---- phase 2: issue reads (a4-7), stagger barrier, consume
        a[4] = *(const bf16x8*)(bufp + offA + 4096);
        a[5] = *(const bf16x8*)(bufp + offA + 5120);
        a[6] = *(const bf16x8*)(bufp + offA + 6144);
        a[7] = *(const bf16x8*)(bufp + offA + 7168);
        __builtin_amdgcn_sched_barrier(0);
        __builtin_amdgcn_s_barrier();
        asm volatile("s_waitcnt lgkmcnt(0)" ::: "memory");
        __builtin_amdgcn_sched_barrier(0);
        __builtin_amdgcn_s_setprio(1);
#pragma unroll
        for (int m = 4; m < 8; m++)
#pragma unroll
            for (int n = 0; n < 4; n++)
                acc[m][n] = __builtin_amdgcn_mfma_f32_16x16x32_bf16(a[m], b[n], acc[m][n], 0, 0, 0);
        __builtin_amdgcn_s_setprio(0);
        __builtin_amdgcn_sched_barrier(0);
        __builtin_amdgcn_s_barrier();          // END: all reads of buf[kt&1] drained
        __builtin_amdgcn_sched_barrier(0);
    }
#undef STAGE

    // epilogue: frag row = (l>>4)*4 + r, col = l&15; n INNERMOST so the four
    // 32B store groups filling one 128B line issue back-to-back (full-sector merge).
    const int row0 = by * 256 + wr * 128 + ((l >> 4) << 2);
    const int col0 = bx * 256 + wc * 64 + (l & 15);
    const int seg = bx >> 1;  // EPI4: 512-col segment (256-tile never straddles)
    const size_t segoff = (size_t)seg * M * 512;
    const int c511 = col0 & 511;
    float bv[4];
#pragma unroll
    for (int n = 0; n < 4; n++) bv[n] = bias[col0 + n * 16];
#pragma unroll
    for (int m = 0; m < 8; m++) {
#pragma unroll
        for (int r = 0; r < 4; r++) {
            const int row = row0 + m * 16 + r;
            const size_t base = (size_t)row * N + col0;
#pragma unroll
            for (int n = 0; n < 4; n++) {
                float vv = acc[m][n][r] + bv[n];
                if constexpr (EPI == 2) {
                    vv = vv > 0.f ? vv : 0.f;
                    out16[base + n * 16] = f2bf(vv);
                } else if constexpr (EPI == 3) {
                    vv += bf2f(res16[base + n * 16]);
                    out16[base + n * 16] = f2bf(vv);
                } else if constexpr (EPI == 4) {
                    if (seg < 2) vv = vv > 0.f ? vv + 1.f : __expf(vv);
                    out16[segoff + (size_t)row * 512 + c511 + n * 16] = f2bf(vv);
                } else {
                    out16[base + n * 16] = f2bf(vv);
                }
            }
        }
    }
}

// ---------------- kv partial reduction ----------------
__global__ __launch_bounds__(256) void kv_partial(
    const ushort* __restrict__ km, const ushort* __restrict__ v,
    float* __restrict__ kvp, float* __restrict__ ksump, int S) {
    __shared__ ushort kms[32 * 64];
    __shared__ ushort vs[32 * 64];
    const int t = threadIdx.x;
    const int bh = blockIdx.y, b = bh >> 3, h = bh & 7;
    const int d0 = (t >> 4) * 4, e0 = (t & 15) * 4;
    float acc[4][4] = {};
    float ks = 0.f;
    const int s_base = blockIdx.x * 512;
    const int r = t >> 3, c8 = (t & 7) * 8;
    for (int s0 = 0; s0 < 512; s0 += 32) {
        size_t grow = ((size_t)b * S + s_base + s0 + r) * 512 + h * 64 + c8;
        *(uint4*)&kms[r * 64 + c8] = *(const uint4*)&km[grow];
        *(uint4*)&vs[r * 64 + c8] = *(const uint4*)&v[grow];
        __syncthreads();
#pragma unroll 4
        for (int s = 0; s < 32; ++s) {
            ushort4 ka = *(const ushort4*)&kms[s * 64 + d0];
            ushort4 vb = *(const ushort4*)&vs[s * 64 + e0];
            float a0 = bf2f(ka.x), a1 = bf2f(ka.y), a2 = bf2f(ka.z), a3 = bf2f(ka.w);
            float b0 = bf2f(vb.x), b1 = bf2f(vb.y), b2 = bf2f(vb.z), b3 = bf2f(vb.w);
            acc[0][0] += a0 * b0; acc[0][1] += a0 * b1; acc[0][2] += a0 * b2; acc[0][3] += a0 * b3;
            acc[1][0] += a1 * b0; acc[1][1] += a1 * b1; acc[1][2] += a1 * b2; acc[1][3] += a1 * b3;
            acc[2][0] += a2 * b0; acc[2][1] += a2 * b1; acc[2][2] += a2 * b2; acc[2][3] += a2 * b3;
            acc[3][0] += a3 * b0; acc[3][1] += a3 * b1; acc[3][2] += a3 * b2; acc[3][3] += a3 * b3;
            if (t < 64) ks += bf2f(kms[s * 64 + t]);
        }
        __syncthreads();
    }
    float* dst = kvp + ((size_t)bh * 16 + blockIdx.x) * 4096;
#pragma unroll
    for (int i = 0; i < 4; i++)
#pragma unroll
        for (int j = 0; j < 4; j++)
            dst[(d0 + i) * 64 + e0 + j] = acc[i][j];
    if (t < 64) ksump[((size_t)bh * 16 + blockIdx.x) * 64 + t] = ks;
}

// reduce partials; kv emitted TRANSPOSED per head as bf16: kvt[bh][e][d]
__global__ void kv_reduce(const float* __restrict__ kvp, const float* __restrict__ ksump,
                          ushort* __restrict__ kvt, float* __restrict__ ksum) {
    int i = blockIdx.x * 256 + threadIdx.x;
    if (i < 32 * 4096) {
        int bh = i >> 12, de = i & 4095;
        int d = de >> 6, e = de & 63;
        float s = 0.f;
#pragma unroll
        for (int c = 0; c < 16; ++c) s += kvp[((size_t)bh * 16 + c) * 4096 + de];
        kvt[(size_t)bh * 4096 + e * 64 + d] = f2bf(s);
    } else {
        int j = i - 32 * 4096;
        if (j < 32 * 64) {
            int bh = j >> 6, d = j & 63;
            float s = 0.f;
#pragma unroll
            for (int c = 0; c < 16; ++c) s += ksump[((size_t)bh * 16 + c) * 64 + d];
            ksum[j] = s;
        }
    }
}

// ---------------- attn via MFMA: per (b,h) attn = qm[S,64] @ kv[64,64], * z ----------------
__global__ __launch_bounds__(256) void attn_mfma(
    const ushort* __restrict__ qm, const ushort* __restrict__ kvt,
    const float* __restrict__ ksum, ushort* __restrict__ attnE, int S) {
    __shared__ ushort As[128 * 128];
    __shared__ ushort Bs[128 * 64];
    __shared__ float zbuf[128][2];
    __shared__ float ks2[128];
    const int t = threadIdx.x, w = t >> 6, l = t & 63;
    const int cx = blockIdx.x, by = blockIdx.y;
    const int b = (by * 128) / S;
    const int h0 = cx * 2;
    const size_t arow0 = (size_t)(by * 128) * 512 + cx * 128;

#pragma unroll
    for (int rd = 0; rd < 8; ++rd) {
        const ushort* g = qm + arow0 + (size_t)(rd * 16 + w * 4 + (l >> 4)) * 512 + (l & 15) * 8;
        gload16(g, (char*)As + rd * 4096 + w * 1024);
    }
    const ushort* kvbase = kvt + (size_t)(b * 8 + h0) * 4096;
#pragma unroll
    for (int rd = 0; rd < 4; ++rd) {
        const ushort* g = kvbase + (rd * 32 + w * 8 + (l >> 3)) * 64 + (l & 7) * 8;
        gload16(g, (char*)Bs + rd * 4096 + w * 1024);
    }
    if (t < 128) ks2[t] = ksum[(b * 8 + h0) * 64 + t];
    __syncthreads();

    {
        const int r = t >> 1, hh = t & 1;
        float den = 0.f;
#pragma unroll
        for (int d0 = 0; d0 < 64; d0 += 8) {
            bf16x8 qv = *(const bf16x8*)&As[r * 128 + hh * 64 + d0];
#pragma unroll
            for (int j = 0; j < 8; j++) den += bf2f((ushort)qv[j]) * ks2[hh * 64 + d0 + j];
        }
        zbuf[r][hh] = 1.0f / (den + 1e-6f);
    }

    const int wr = w >> 1, wc = w & 1;
    const int ar = wr * 64 + (l & 15);
    const int br = wc * 64 + (l & 15);
    const int ko = (l >> 4) * 8;
    f32x4 acc[4][4] = {};
#pragma unroll
    for (int ks_ = 0; ks_ < 2; ++ks_) {
        bf16x8 a[4], bb[4];
#pragma unroll
        for (int m = 0; m < 4; m++)
            a[m] = *(const bf16x8*)&As[(ar + m * 16) * 128 + wc * 64 + ks_ * 32 + ko];
#pragma unroll
        for (int n = 0; n < 4; n++)
            bb[n] = *(const bf16x8*)&Bs[(br + n * 16) * 64 + ks_ * 32 + ko];
#pragma unroll
        for (int m = 0; m < 4; m++)
#pragma unroll
            for (int n = 0; n < 4; n++)
                acc[m][n] = __builtin_amdgcn_mfma_f32_16x16x32_bf16(a[m], bb[n], acc[m][n], 0, 0, 0);
    }
    __syncthreads();

    const int row0l = wr * 64 + ((l >> 4) << 2);
    ushort* outbase = attnE + (size_t)(by * 128) * 512 + cx * 128;
#pragma unroll
    for (int n = 0; n < 4; n++) {
#pragma unroll
        for (int m = 0; m < 4; m++) {
#pragma unroll
            for (int r = 0; r < 4; r++) {
                int rl = row0l + m * 16 + r;
                float z = zbuf[rl][wc];
                outbase[(size_t)rl * 512 + wc * 64 + n * 16 + (l & 15)] = f2bf(acc[m][n][r] * z);
            }
        }
    }
}

// ---------------- LayerNorm over bf16 input ----------------
template <int OUT32>
__global__ __launch_bounds__(256) void ln_bf16(
    const ushort* __restrict__ in, const float* __restrict__ g, const float* __restrict__ be,
    void* __restrict__ outp, int Mrows) {
    const int w = threadIdx.x >> 6, l = threadIdx.x & 63;
    const int row = blockIdx.x * 4 + w;
    if (row >= Mrows) return;
    const ushort* rp = in + (size_t)row * 512;
    uint4 u = *(const uint4*)&rp[l * 8];
    float x[8];
    x[0] = bf2f((ushort)(u.x & 0xffff)); x[1] = bf2f((ushort)(u.x >> 16));
    x[2] = bf2f((ushort)(u.y & 0xffff)); x[3] = bf2f((ushort)(u.y >> 16));
    x[4] = bf2f((ushort)(u.z & 0xffff)); x[5] = bf2f((ushort)(u.z >> 16));
    x[6] = bf2f((ushort)(u.w & 0xffff)); x[7] = bf2f((ushort)(u.w >> 16));
    float s = 0.f, ss = 0.f;
#pragma unroll
    for (int j = 0; j < 8; j++) { s += x[j]; ss += x[j] * x[j]; }
#pragma unroll
    for (int o = 1; o < 64; o <<= 1) {
        s += __shfl_xor(s, o, 64);
        ss += __shfl_xor(ss, o, 64);
    }
    float mean = s * (1.f / 512.f);
    float var = ss * (1.f / 512.f) - mean * mean;
    float rstd = rsqrtf(var + 1e-5f);
    float4 g0 = *(const float4*)&g[l * 8], g1v = *(const float4*)&g[l * 8 + 4];
    float4 b0 = *(const float4*)&be[l * 8], b1v = *(const float4*)&be[l * 8 + 4];
    float o0[8];
    o0[0] = (x[0] - mean) * rstd * g0.x + b0.x;
    o0[1] = (x[1] - mean) * rstd * g0.y + b0.y;
    o0[2] = (x[2] - mean) * rstd * g0.z + b0.z;
    o0[3] = (x[3] - mean) * rstd * g0.w + b0.w;
    o0[4] = (x[4] - mean) * rstd * g1v.x + b1v.x;
    o0[5] = (x[5] - mean) * rstd * g1v.y + b1v.y;
    o0[6] = (x[6] - mean) * rstd * g1v.z + b1v.z;
    o0[7] = (x[7] - mean) * rstd * g1v.w + b1v.w;
    if constexpr (OUT32) {
        float* op = (float*)outp + (size_t)row * 512;
        *(float4*)&op[l * 8] = make_float4(o0[0], o0[1], o0[2], o0[3]);
        *(float4*)&op[l * 8 + 4] = make_float4(o0[4], o0[5], o0[6], o0[7]);
    } else {
        ushort* op = (ushort*)outp + (size_t)row * 512;
        ushort4 u0, u1;
        u0.x = f2bf(o0[0]); u0.y = f2bf(o0[1]); u0.z = f2bf(o0[2]); u0.w = f2bf(o0[3]);
        u1.x = f2bf(o0[4]); u1.y = f2bf(o0[5]); u1.z = f2bf(o0[6]); u1.w = f2bf(o0[7]);
        *(ushort4*)&op[l * 8] = u0;
        *(ushort4*)&op[l * 8 + 4] = u1;
    }
}

extern "C" void kernel_launch(void* const* d_in, const int* in_sizes, int n_in,
                              void* d_out, int out_size, void* d_ws, size_t ws_size,
                              hipStream_t stream) {
    const int B = 4, S = 8192, E = 512, F = 2048;
    const int M = B * S;  // 32768
    const size_t SZ = (size_t)M * E * 2;  // 32 MiB
    const int SMEM = 65536;

    const float* src = (const float*)d_in[0];
    const float* Wq = (const float*)d_in[1];  const float* bq = (const float*)d_in[2];
    const float* Wk = (const float*)d_in[3];  const float* bk = (const float*)d_in[4];
    const float* Wv = (const float*)d_in[5];  const float* bv = (const float*)d_in[6];
    const float* Wo = (const float*)d_in[7];  const float* bo = (const float*)d_in[8];
    const float* W1 = (const float*)d_in[9];  const float* b1 = (const float*)d_in[10];
    const float* W2 = (const float*)d_in[11]; const float* b2 = (const float*)d_in[12];
    const float* g1 = (const float*)d_in[13]; const float* be1 = (const float*)d_in[14];
    const float* g2 = (const float*)d_in[15]; const float* be2 = (const float*)d_in[16];

    char* ws = (char*)d_ws;
    ushort* qm    = (ushort*)(ws + 0 * SZ);
    ushort* km    = (ushort*)(ws + 1 * SZ);
    ushort* v     = (ushort*)(ws + 2 * SZ);
    ushort* src16 = (ushort*)(ws + 3 * SZ);
    ushort* x16   = (ushort*)(ws + 4 * SZ);
    ushort* z16   = (ushort*)(ws + 5 * SZ);
    char*   tail  = ws + 6 * SZ;
    float*  kvp   = (float*)(tail);
    float*  ksump = (float*)(tail + 8388608);
    ushort* kvt   = (ushort*)(tail + 8519680);
    float*  ksum  = (float*)(tail + 8781824);
    float*  bqkv  = (float*)(tail + 8790016);
    ushort* wqkv  = (ushort*)(tail + 8796160);
    ushort* wot   = (ushort*)(tail + 10369024);
    ushort* w1t   = (ushort*)(tail + 10893312);
    ushort* w2t   = (ushort*)(tail + 12990464);
    ushort* attnE = km;
    ushort* y16   = v;
    ushort* hbuf  = (ushort*)(ws + 0);

    hipFuncSetAttribute((const void*)gemm256<2>, hipFuncAttributeMaxDynamicSharedMemorySize, SMEM);
    hipFuncSetAttribute((const void*)gemm256<3>, hipFuncAttributeMaxDynamicSharedMemorySize, SMEM);
    hipFuncSetAttribute((const void*)gemm256<4>, hipFuncAttributeMaxDynamicSharedMemorySize, SMEM);

    // 1) converts
    conv_bf16<<<dim3((M * E / 4 + 255) / 256), 256, 0, stream>>>(src, src16, M * E / 4);
    wconv_t<<<dim3(E / 32, E / 32), 256, 0, stream>>>(Wq, wqkv, E, E);
    wconv_t<<<dim3(E / 32, E / 32), 256, 0, stream>>>(Wk, wqkv + 512 * 512, E, E);
    wconv_t<<<dim3(E / 32, E / 32), 256, 0, stream>>>(Wv, wqkv + 1024 * 512, E, E);
    wconv_t<<<dim3(E / 32, E / 32), 256, 0, stream>>>(Wo, wot, E, E);
    wconv_t<<<dim3(F / 32, E / 32), 256, 0, stream>>>(W1, w1t, E, F);
    wconv_t<<<dim3(E / 32, F / 32), 256, 0, stream>>>(W2, w2t, F, E);
    biascat<<<dim3(6), 256, 0, stream>>>(bq, bk, bv, bqkv);

    // 2) fused QKV GEMM (N=1536; elu+1 on q,k segments)
    gemm256<4><<<dim3(6 * 128), 512, SMEM, stream>>>(src16, wqkv, bqkv, nullptr, qm, M, 1536, E, 6);

    // 3) kv / ksum reduction
    kv_partial<<<dim3(16, 32), 256, 0, stream>>>(km, v, kvp, ksump, S);
    kv_reduce<<<dim3((32 * 4096 + 32 * 64 + 255) / 256), 256, 0, stream>>>(kvp, ksump, kvt, ksum);

    // 4) attention combine (MFMA)
    attn_mfma<<<dim3(4, M / 128), 256, 0, stream>>>(qm, kvt, ksum, attnE, S);

    // 5) output proj + bf16 residual, then LN -> x16
    gemm256<3><<<dim3(2 * 128), 512, SMEM, stream>>>(attnE, wot, bo, src16, y16, M, E, E, 2);
    ln_bf16<0><<<dim3(M / 4), 256, 0, stream>>>(y16, g1, be1, x16, M);

    // 6) FFN
    gemm256<2><<<dim3(8 * 128), 512, SMEM, stream>>>(x16, w1t, b1, nullptr, hbuf, M, F, E, 8);
    gemm256<3><<<dim3(2 * 128), 512, SMEM, stream>>>(hbuf, w2t, b2, x16, z16, M, E, F, 2);
    ln_bf16<1><<<dim3(M / 4), 256, 0, stream>>>(z16, g2, be2, (float*)d_out, M);
}

// Round 8
// 393.741 us; speedup vs baseline: 5.6954x; 5.6954x over previous
//
#include <hip/hip_runtime.h>
#include <hip/hip_bf16.h>

typedef __attribute__((ext_vector_type(8))) short bf16x8;
typedef __attribute__((ext_vector_type(4))) float f32x4;

__device__ inline ushort f2bf(float f) {
    uint u = __float_as_uint(f);
    u += 0x7fff + ((u >> 16) & 1);
    return (ushort)(u >> 16);
}
__device__ inline float bf2f(ushort h) {
    return __uint_as_float(((uint)h) << 16);
}

__device__ inline void gload16(const void* g, void* lds) {
    __builtin_amdgcn_global_load_lds(
        (const __attribute__((address_space(1))) void*)g,
        (__attribute__((address_space(3))) void*)lds, 16, 0, 0);
}

// ---------------- converts ----------------
__global__ void conv_bf16(const float* __restrict__ in, ushort* __restrict__ out, int n4) {
    int i = blockIdx.x * 256 + threadIdx.x;
    if (i >= n4) return;
    float4 a = ((const float4*)in)[i];
    ushort4 o;
    o.x = f2bf(a.x); o.y = f2bf(a.y); o.z = f2bf(a.z); o.w = f2bf(a.w);
    ((ushort4*)out)[i] = o;
}

// in: fp32 [K,N] -> out: bf16 [N,K]
__global__ void wconv_t(const float* __restrict__ in, ushort* __restrict__ out, int K, int N) {
    __shared__ float tile[32][33];
    int kb = blockIdx.y * 32, nb = blockIdx.x * 32;
    int tx = threadIdx.x & 31, ty = threadIdx.x >> 5;  // 32 x 8
#pragma unroll
    for (int i = 0; i < 4; i++)
        tile[ty + i * 8][tx] = in[(size_t)(kb + ty + i * 8) * N + nb + tx];
    __syncthreads();
#pragma unroll
    for (int i = 0; i < 4; i++) {
        int n = nb + ty + i * 8, k = kb + tx;
        out[(size_t)n * K + k] = f2bf(tile[tx][ty + i * 8]);
    }
}

__global__ void biascat(const float* __restrict__ a, const float* __restrict__ b,
                        const float* __restrict__ c, float* __restrict__ o) {
    int i = blockIdx.x * 256 + threadIdx.x;
    if (i < 512) o[i] = a[i];
    else if (i < 1024) o[i] = b[i - 512];
    else if (i < 1536) o[i] = c[i - 1024];
}

// ============ 256x256 deep-pipelined GEMM (Kt-large shapes; 1 block/CU) ============
// PROVEN round-6 config: (512,2), BK=32, 4-buffer 128KB, 3-deep prefetch, counted
// vmcnt, phased ds_read/MFMA. Race argument as in round 5/6 comments.
template <int EPI>
__global__ __launch_bounds__(512, 2) void gemm256(
    const ushort* __restrict__ A, const ushort* __restrict__ Bt,
    const float* __restrict__ bias, const ushort* __restrict__ res16,
    ushort* __restrict__ out16, int M, int N, int K, int nbx) {
    extern __shared__ char smem[];  // 4 * 32768
    const int t = threadIdx.x;
    const int w = t >> 6, l = t & 63;
    const int wr = w >> 2, wc = w & 3;
    const int nwg = gridDim.x;
    const int cpx = nwg >> 3;
    const int swz = (blockIdx.x & 7) * cpx + (blockIdx.x >> 3);
    const int bx = swz % nbx, by = swz / nbx;

    const int sc = (t & 3) ^ ((t >> 3) & 3);
    const ushort* gA0 = A + (size_t)(by * 256 + (t >> 2)) * K + sc * 8;
    const ushort* gA1 = gA0 + (size_t)128 * K;
    const ushort* gB0 = Bt + (size_t)(bx * 256 + (t >> 2)) * K + sc * 8;
    const ushort* gB1 = gB0 + (size_t)128 * K;

#define STAGE_H0(kt)                                          \
    {                                                         \
        char* Lb = smem + ((kt) & 3) * 32768 + (w << 10);     \
        const int ko_ = (kt) * 32;                            \
        gload16(gA0 + ko_, Lb);                               \
        gload16(gB0 + ko_, Lb + 16384);                       \
    }
#define STAGE_H1(kt)                                          \
    {                                                         \
        char* Lb = smem + ((kt) & 3) * 32768 + (w << 10);     \
        const int ko_ = (kt) * 32;                            \
        gload16(gA1 + ko_, Lb + 8192);                        \
        gload16(gB1 + ko_, Lb + 24576);                       \
    }

    f32x4 acc[8][4] = {};
    const int Kt = K >> 5;

    const int R0a = wr * 128 + (l & 15);
    const int offA = R0a * 64 + (((l >> 4) ^ ((R0a >> 1) & 3)) << 4);
    const int R0b = wc * 64 + (l & 15);
    const int offB = 16384 + R0b * 64 + (((l >> 4) ^ ((R0b >> 1) & 3)) << 4);

    STAGE_H0(0); STAGE_H1(0);
    STAGE_H0(1); STAGE_H1(1);
    STAGE_H0(2); STAGE_H1(2);

#pragma unroll 1
    for (int kt = 0; kt < Kt; ++kt) {
        const int rem = Kt - 1 - kt;
        if (rem >= 2)      asm volatile("s_waitcnt vmcnt(8)" ::: "memory");
        else if (rem == 1) asm volatile("s_waitcnt vmcnt(4)" ::: "memory");
        else               asm volatile("s_waitcnt vmcnt(0)" ::: "memory");
        __builtin_amdgcn_s_barrier();
        __builtin_amdgcn_sched_barrier(0);

        const char* bufp = smem + (kt & 3) * 32768;
        bf16x8 a[8], b[4];
        b[0] = *(const bf16x8*)(bufp + offB);
        b[1] = *(const bf16x8*)(bufp + offB + 1024);
        b[2] = *(const bf16x8*)(bufp + offB + 2048);
        b[3] = *(const bf16x8*)(bufp + offB + 3072);
        a[0] = *(const bf16x8*)(bufp + offA);
        a[1] = *(const bf16x8*)(bufp + offA + 1024);
        a[2] = *(const bf16x8*)(bufp + offA + 2048);
        a[3] = *(const bf16x8*)(bufp + offA + 3072);
        if (kt + 3 < Kt) STAGE_H0(kt + 3);
        __builtin_amdgcn_sched_barrier(0);
        __builtin_amdgcn_s_barrier();
        asm volatile("s_waitcnt lgkmcnt(0)" ::: "memory");
        __builtin_amdgcn_sched_barrier(0);
        __builtin_amdgcn_s_setprio(1);
#pragma unroll
        for (int m = 0; m < 4; m++)
#pragma unroll
            for (int n = 0; n < 4; n++)
                acc[m][n] = __builtin_amdgcn_mfma_f32_16x16x32_bf16(a[m], b[n], acc[m][n], 0, 0, 0);
        __builtin_amdgcn_s_setprio(0);
        __builtin_amdgcn_sched_barrier(0);
        a[4] = *(const bf16x8*)(bufp + offA + 4096);
        a[5] = *(const bf16x8*)(bufp + offA + 5120);
        a[6] = *(const bf16x8*)(bufp + offA + 6144);
        a[7] = *(const bf16x8*)(bufp + offA + 7168);
        if (kt + 3 < Kt) STAGE_H1(kt + 3);
        __builtin_amdgcn_sched_barrier(0);
        __builtin_amdgcn_s_barrier();
        asm volatile("s_waitcnt lgkmcnt(0)" ::: "memory");
        __builtin_amdgcn_sched_barrier(0);
        __builtin_amdgcn_s_setprio(1);
#pragma unroll
        for (int m = 4; m < 8; m++)
#pragma unroll
            for (int n = 0; n < 4; n++)
                acc[m][n] = __builtin_amdgcn_mfma_f32_16x16x32_bf16(a[m], b[n], acc[m][n], 0, 0, 0);
        __builtin_amdgcn_s_setprio(0);
        __builtin_amdgcn_sched_barrier(0);
    }
#undef STAGE_H0
#undef STAGE_H1

    const int row0 = by * 256 + wr * 128 + ((l >> 4) << 2);
    const int col0 = bx * 256 + wc * 64 + (l & 15);
    const int seg = bx >> 1;
    const size_t segoff = (size_t)seg * M * 512;
    const int c511 = col0 & 511;
    float bv[4];
#pragma unroll
    for (int n = 0; n < 4; n++) bv[n] = bias[col0 + n * 16];
#pragma unroll
    for (int m = 0; m < 8; m++) {
#pragma unroll
        for (int r = 0; r < 4; r++) {
            const int row = row0 + m * 16 + r;
            const size_t base = (size_t)row * N + col0;
#pragma unroll
            for (int n = 0; n < 4; n++) {
                float vv = acc[m][n][r] + bv[n];
                if constexpr (EPI == 2) {
                    vv = vv > 0.f ? vv : 0.f;
                    out16[base + n * 16] = f2bf(vv);
                } else if constexpr (EPI == 3) {
                    vv += bf2f(res16[base + n * 16]);
                    out16[base + n * 16] = f2bf(vv);
                } else if constexpr (EPI == 4) {
                    if (seg < 2) vv = vv > 0.f ? vv + 1.f : __expf(vv);
                    out16[segoff + (size_t)row * 512 + c511 + n * 16] = f2bf(vv);
                } else {
                    out16[base + n * 16] = f2bf(vv);
                }
            }
        }
    }
}

// ============ 128x128 phased GEMM (Kt=16 shapes; 2-3 independent blocks/CU) ============
// 256 threads (4 waves, 2Mx2N; 64x64/wave), BK=32, 2-buffer 32KB dynamic LDS, 1-deep
// prefetch, same phase skeleton as gemm256. acc[4][4]=64 AGPR keeps total regs/wave
// ~165 so 2-3 blocks co-reside: waves on a SIMD come from DIFFERENT blocks and are
// not barrier-locked -> one block's MFMA covers another's prologue/epilogue/stage
// stalls (the round-6 structural gap at 1 block/CU).
// Race safety (2-buffer, 1-deep):
//  - STAGE(kt+1) at iter-kt top writes buf[(kt-1)&1]; all waves drained lgkmcnt(0)
//    on buf[kt-1] reads before iter kt-1's END barrier, which precedes this STAGE.
//  - vmcnt(4) after STAGE(kt+1): stage(kt) fully landed; top barrier publishes it.
//  - END barrier per iter protects the next STAGE's write target.
template <int EPI>
__global__ __launch_bounds__(256) void gemm128(
    const ushort* __restrict__ A, const ushort* __restrict__ Bt,
    const float* __restrict__ bias, const ushort* __restrict__ res16,
    ushort* __restrict__ out16, int M, int N, int K, int nbx) {
    extern __shared__ char smem[];  // 2 * 16384
    const int t = threadIdx.x;
    const int w = t >> 6, l = t & 63;
    const int wr = w >> 1, wc = w & 1;
    const int nwg = gridDim.x;
    const int cpx = nwg >> 3;
    const int swz = (blockIdx.x & 7) * cpx + (blockIdx.x >> 3);
    const int bx = swz % nbx, by = swz / nbx;

    // staging: thread t covers storage bytes t*16 of each 4KB quarter (64 rows x 64B).
    // storage row = t>>2, chunk = t&3; source logical chunk = (t&3)^((row>>1)&3)
    const int sc = (t & 3) ^ ((t >> 3) & 3);
    const ushort* gA0 = A + (size_t)(by * 128 + (t >> 2)) * K + sc * 8;
    const ushort* gA1 = gA0 + (size_t)64 * K;
    const ushort* gB0 = Bt + (size_t)(bx * 128 + (t >> 2)) * K + sc * 8;
    const ushort* gB1 = gB0 + (size_t)64 * K;

#define STAGE(kt)                                             \
    {                                                         \
        char* Lb = smem + ((kt) & 1) * 16384 + (w << 10);     \
        const int ko_ = (kt) * 32;                            \
        gload16(gA0 + ko_, Lb);                               \
        gload16(gA1 + ko_, Lb + 4096);                        \
        gload16(gB0 + ko_, Lb + 8192);                        \
        gload16(gB1 + ko_, Lb + 12288);                       \
    }

    f32x4 acc[4][4] = {};
    const int Kt = K >> 5;

    const int R0a = wr * 64 + (l & 15);
    const int offA = R0a * 64 + (((l >> 4) ^ ((R0a >> 1) & 3)) << 4);
    const int R0b = wc * 64 + (l & 15);
    const int offB = 8192 + R0b * 64 + (((l >> 4) ^ ((R0b >> 1) & 3)) << 4);

    STAGE(0);

#pragma unroll 1
    for (int kt = 0; kt < Kt; ++kt) {
        if (kt + 1 < Kt) {
            STAGE(kt + 1);
            asm volatile("s_waitcnt vmcnt(4)" ::: "memory");
        } else {
            asm volatile("s_waitcnt vmcnt(0)" ::: "memory");
        }
        __builtin_amdgcn_s_barrier();          // stage(kt) visible to all waves
        __builtin_amdgcn_sched_barrier(0);

        const char* bufp = smem + (kt & 1) * 16384;
        bf16x8 a[4], b[4];
        // phase 1: issue b0-3, a0-1; stagger barrier; consume
        b[0] = *(const bf16x8*)(bufp + offB);
        b[1] = *(const bf16x8*)(bufp + offB + 1024);
        b[2] = *(const bf16x8*)(bufp + offB + 2048);
        b[3] = *(const bf16x8*)(bufp + offB + 3072);
        a[0] = *(const bf16x8*)(bufp + offA);
        a[1] = *(const bf16x8*)(bufp + offA + 1024);
        __builtin_amdgcn_sched_barrier(0);
        __builtin_amdgcn_s_barrier();
        asm volatile("s_waitcnt lgkmcnt(0)" ::: "memory");
        __builtin_amdgcn_sched_barrier(0);
        __builtin_amdgcn_s_setprio(1);
#pragma unroll
        for (int m = 0; m < 2; m++)
#pragma unroll
            for (int n = 0; n < 4; n++)
                acc[m][n] = __builtin_amdgcn_mfma_f32_16x16x32_bf16(a[m], b[n], acc[m][n], 0, 0, 0);
        __builtin_amdgcn_s_setprio(0);
        __builtin_amdgcn_sched_barrier(0);
        // phase 2: issue a2-3; stagger barrier; consume
        a[2] = *(const bf16x8*)(bufp + offA + 2048);
        a[3] = *(const bf16x8*)(bufp + offA + 3072);
        __builtin_amdgcn_sched_barrier(0);
        __builtin_amdgcn_s_barrier();
        asm volatile("s_waitcnt lgkmcnt(0)" ::: "memory");
        __builtin_amdgcn_sched_barrier(0);
        __builtin_amdgcn_s_setprio(1);
#pragma unroll
        for (int m = 2; m < 4; m++)
#pragma unroll
            for (int n = 0; n < 4; n++)
                acc[m][n] = __builtin_amdgcn_mfma_f32_16x16x32_bf16(a[m], b[n], acc[m][n], 0, 0, 0);
        __builtin_amdgcn_s_setprio(0);
        __builtin_amdgcn_sched_barrier(0);
        __builtin_amdgcn_s_barrier();          // END: all reads of buf[kt&1] drained
        __builtin_amdgcn_sched_barrier(0);
    }
#undef STAGE

    const int row0 = by * 128 + wr * 64 + ((l >> 4) << 2);
    const int col0 = bx * 128 + wc * 64 + (l & 15);
    const int seg = bx >> 2;  // EPI4: 512-col segment (128-tile never straddles)
    const size_t segoff = (size_t)seg * M * 512;
    const int c511 = col0 & 511;
    float bv[4];
#pragma unroll
    for (int n = 0; n < 4; n++) bv[n] = bias[col0 + n * 16];
#pragma unroll
    for (int m = 0; m < 4; m++) {
#pragma unroll
        for (int r = 0; r < 4; r++) {
            const int row = row0 + m * 16 + r;
            const size_t base = (size_t)row * N + col0;
#pragma unroll
            for (int n = 0; n < 4; n++) {
                float vv = acc[m][n][r] + bv[n];
                if constexpr (EPI == 2) {
                    vv = vv > 0.f ? vv : 0.f;
                    out16[base + n * 16] = f2bf(vv);
                } else if constexpr (EPI == 3) {
                    vv += bf2f(res16[base + n * 16]);
                    out16[base + n * 16] = f2bf(vv);
                } else if constexpr (EPI == 4) {
                    if (seg < 2) vv = vv > 0.f ? vv + 1.f : __expf(vv);
                    out16[segoff + (size_t)row * 512 + c511 + n * 16] = f2bf(vv);
                } else {
                    out16[base + n * 16] = f2bf(vv);
                }
            }
        }
    }
}

// ---------------- kv partial reduction ----------------
__global__ __launch_bounds__(256) void kv_partial(
    const ushort* __restrict__ km, const ushort* __restrict__ v,
    float* __restrict__ kvp, float* __restrict__ ksump, int S) {
    __shared__ ushort kms[32 * 64];
    __shared__ ushort vs[32 * 64];
    const int t = threadIdx.x;
    const int bh = blockIdx.y, b = bh >> 3, h = bh & 7;
    const int d0 = (t >> 4) * 4, e0 = (t & 15) * 4;
    float acc[4][4] = {};
    float ks = 0.f;
    const int s_base = blockIdx.x * 512;
    const int r = t >> 3, c8 = (t & 7) * 8;
    for (int s0 = 0; s0 < 512; s0 += 32) {
        size_t grow = ((size_t)b * S + s_base + s0 + r) * 512 + h * 64 + c8;
        *(uint4*)&kms[r * 64 + c8] = *(const uint4*)&km[grow];
        *(uint4*)&vs[r * 64 + c8] = *(const uint4*)&v[grow];
        __syncthreads();
#pragma unroll 4
        for (int s = 0; s < 32; ++s) {
            ushort4 ka = *(const ushort4*)&kms[s * 64 + d0];
            ushort4 vb = *(const ushort4*)&vs[s * 64 + e0];
            float a0 = bf2f(ka.x), a1 = bf2f(ka.y), a2 = bf2f(ka.z), a3 = bf2f(ka.w);
            float b0 = bf2f(vb.x), b1 = bf2f(vb.y), b2 = bf2f(vb.z), b3 = bf2f(vb.w);
            acc[0][0] += a0 * b0; acc[0][1] += a0 * b1; acc[0][2] += a0 * b2; acc[0][3] += a0 * b3;
            acc[1][0] += a1 * b0; acc[1][1] += a1 * b1; acc[1][2] += a1 * b2; acc[1][3] += a1 * b3;
            acc[2][0] += a2 * b0; acc[2][1] += a2 * b1; acc[2][2] += a2 * b2; acc[2][3] += a2 * b3;
            acc[3][0] += a3 * b0; acc[3][1] += a3 * b1; acc[3][2] += a3 * b2; acc[3][3] += a3 * b3;
            if (t < 64) ks += bf2f(kms[s * 64 + t]);
        }
        __syncthreads();
    }
    float* dst = kvp + ((size_t)bh * 16 + blockIdx.x) * 4096;
#pragma unroll
    for (int i = 0; i < 4; i++)
#pragma unroll
        for (int j = 0; j < 4; j++)
            dst[(d0 + i) * 64 + e0 + j] = acc[i][j];
    if (t < 64) ksump[((size_t)bh * 16 + blockIdx.x) * 64 + t] = ks;
}

// reduce partials; kv emitted TRANSPOSED per head as bf16: kvt[bh][e][d]
__global__ void kv_reduce(const float* __restrict__ kvp, const float* __restrict__ ksump,
                          ushort* __restrict__ kvt, float* __restrict__ ksum) {
    int i = blockIdx.x * 256 + threadIdx.x;
    if (i < 32 * 4096) {
        int bh = i >> 12, de = i & 4095;
        int d = de >> 6, e = de & 63;
        float s = 0.f;
#pragma unroll
        for (int c = 0; c < 16; ++c) s += kvp[((size_t)bh * 16 + c) * 4096 + de];
        kvt[(size_t)bh * 4096 + e * 64 + d] = f2bf(s);
    } else {
        int j = i - 32 * 4096;
        if (j < 32 * 64) {
            int bh = j >> 6, d = j & 63;
            float s = 0.f;
#pragma unroll
            for (int c = 0; c < 16; ++c) s += ksump[((size_t)bh * 16 + c) * 64 + d];
            ksum[j] = s;
        }
    }
}

// ---------------- attn via MFMA: per (b,h) attn = qm[S,64] @ kv[64,64], * z ----------------
__global__ __launch_bounds__(256) void attn_mfma(
    const ushort* __restrict__ qm, const ushort* __restrict__ kvt,
    const float* __restrict__ ksum, ushort* __restrict__ attnE, int S) {
    __shared__ ushort As[128 * 128];
    __shared__ ushort Bs[128 * 64];
    __shared__ float zbuf[128][2];
    __shared__ float ks2[128];
    const int t = threadIdx.x, w = t >> 6, l = t & 63;
    const int cx = blockIdx.x, by = blockIdx.y;
    const int b = (by * 128) / S;
    const int h0 = cx * 2;
    const size_t arow0 = (size_t)(by * 128) * 512 + cx * 128;

#pragma unroll
    for (int rd = 0; rd < 8; ++rd) {
        const ushort* g = qm + arow0 + (size_t)(rd * 16 + w * 4 + (l >> 4)) * 512 + (l & 15) * 8;
        gload16(g, (char*)As + rd * 4096 + w * 1024);
    }
    const ushort* kvbase = kvt + (size_t)(b * 8 + h0) * 4096;
#pragma unroll
    for (int rd = 0; rd < 4; ++rd) {
        const ushort* g = kvbase + (rd * 32 + w * 8 + (l >> 3)) * 64 + (l & 7) * 8;
        gload16(g, (char*)Bs + rd * 4096 + w * 1024);
    }
    if (t < 128) ks2[t] = ksum[(b * 8 + h0) * 64 + t];
    __syncthreads();

    {
        const int r = t >> 1, hh = t & 1;
        float den = 0.f;
#pragma unroll
        for (int d0 = 0; d0 < 64; d0 += 8) {
            bf16x8 qv = *(const bf16x8*)&As[r * 128 + hh * 64 + d0];
#pragma unroll
            for (int j = 0; j < 8; j++) den += bf2f((ushort)qv[j]) * ks2[hh * 64 + d0 + j];
        }
        zbuf[r][hh] = 1.0f / (den + 1e-6f);
    }

    const int wr = w >> 1, wc = w & 1;
    const int ar = wr * 64 + (l & 15);
    const int br = wc * 64 + (l & 15);
    const int ko = (l >> 4) * 8;
    f32x4 acc[4][4] = {};
#pragma unroll
    for (int ks_ = 0; ks_ < 2; ++ks_) {
        bf16x8 a[4], bb[4];
#pragma unroll
        for (int m = 0; m < 4; m++)
            a[m] = *(const bf16x8*)&As[(ar + m * 16) * 128 + wc * 64 + ks_ * 32 + ko];
#pragma unroll
        for (int n = 0; n < 4; n++)
            bb[n] = *(const bf16x8*)&Bs[(br + n * 16) * 64 + ks_ * 32 + ko];
#pragma unroll
        for (int m = 0; m < 4; m++)
#pragma unroll
            for (int n = 0; n < 4; n++)
                acc[m][n] = __builtin_amdgcn_mfma_f32_16x16x32_bf16(a[m], bb[n], acc[m][n], 0, 0, 0);
    }
    __syncthreads();

    const int row0l = wr * 64 + ((l >> 4) << 2);
    ushort* outbase = attnE + (size_t)(by * 128) * 512 + cx * 128;
#pragma unroll
    for (int n = 0; n < 4; n++) {
#pragma unroll
        for (int m = 0; m < 4; m++) {
#pragma unroll
            for (int r = 0; r < 4; r++) {
                int rl = row0l + m * 16 + r;
                float z = zbuf[rl][wc];
                outbase[(size_t)rl * 512 + wc * 64 + n * 16 + (l & 15)] = f2bf(acc[m][n][r] * z);
            }
        }
    }
}

// ---------------- LayerNorm over bf16 input ----------------
template <int OUT32>
__global__ __launch_bounds__(256) void ln_bf16(
    const ushort* __restrict__ in, const float* __restrict__ g, const float* __restrict__ be,
    void* __restrict__ outp, int Mrows) {
    const int w = threadIdx.x >> 6, l = threadIdx.x & 63;
    const int row = blockIdx.x * 4 + w;
    if (row >= Mrows) return;
    const ushort* rp = in + (size_t)row * 512;
    uint4 u = *(const uint4*)&rp[l * 8];
    float x[8];
    x[0] = bf2f((ushort)(u.x & 0xffff)); x[1] = bf2f((ushort)(u.x >> 16));
    x[2] = bf2f((ushort)(u.y & 0xffff)); x[3] = bf2f((ushort)(u.y >> 16));
    x[4] = bf2f((ushort)(u.z & 0xffff)); x[5] = bf2f((ushort)(u.z >> 16));
    x[6] = bf2f((ushort)(u.w & 0xffff)); x[7] = bf2f((ushort)(u.w >> 16));
    float s = 0.f, ss = 0.f;
#pragma unroll
    for (int j = 0; j < 8; j++) { s += x[j]; ss += x[j] * x[j]; }
#pragma unroll
    for (int o = 1; o < 64; o <<= 1) {
        s += __shfl_xor(s, o, 64);
        ss += __shfl_xor(ss, o, 64);
    }
    float mean = s * (1.f / 512.f);
    float var = ss * (1.f / 512.f) - mean * mean;
    float rstd = rsqrtf(var + 1e-5f);
    float4 g0 = *(const float4*)&g[l * 8], g1v = *(const float4*)&g[l * 8 + 4];
    float4 b0 = *(const float4*)&be[l * 8], b1v = *(const float4*)&be[l * 8 + 4];
    float o0[8];
    o0[0] = (x[0] - mean) * rstd * g0.x + b0.x;
    o0[1] = (x[1] - mean) * rstd * g0.y + b0.y;
    o0[2] = (x[2] - mean) * rstd * g0.z + b0.z;
    o0[3] = (x[3] - mean) * rstd * g0.w + b0.w;
    o0[4] = (x[4] - mean) * rstd * g1v.x + b1v.x;
    o0[5] = (x[5] - mean) * rstd * g1v.y + b1v.y;
    o0[6] = (x[6] - mean) * rstd * g1v.z + b1v.z;
    o0[7] = (x[7] - mean) * rstd * g1v.w + b1v.w;
    if constexpr (OUT32) {
        float* op = (float*)outp + (size_t)row * 512;
        *(float4*)&op[l * 8] = make_float4(o0[0], o0[1], o0[2], o0[3]);
        *(float4*)&op[l * 8 + 4] = make_float4(o0[4], o0[5], o0[6], o0[7]);
    } else {
        ushort* op = (ushort*)outp + (size_t)row * 512;
        ushort4 u0, u1;
        u0.x = f2bf(o0[0]); u0.y = f2bf(o0[1]); u0.z = f2bf(o0[2]); u0.w = f2bf(o0[3]);
        u1.x = f2bf(o0[4]); u1.y = f2bf(o0[5]); u1.z = f2bf(o0[6]); u1.w = f2bf(o0[7]);
        *(ushort4*)&op[l * 8] = u0;
        *(ushort4*)&op[l * 8 + 4] = u1;
    }
}

extern "C" void kernel_launch(void* const* d_in, const int* in_sizes, int n_in,
                              void* d_out, int out_size, void* d_ws, size_t ws_size,
                              hipStream_t stream) {
    const int B = 4, S = 8192, E = 512, F = 2048;
    const int M = B * S;  // 32768
    const size_t SZ = (size_t)M * E * 2;  // 32 MiB
    const int SMEM256 = 131072;
    const int SMEM128 = 32768;

    const float* src = (const float*)d_in[0];
    const float* Wq = (const float*)d_in[1];  const float* bq = (const float*)d_in[2];
    const float* Wk = (const float*)d_in[3];  const float* bk = (const float*)d_in[4];
    const float* Wv = (const float*)d_in[5];  const float* bv = (const float*)d_in[6];
    const float* Wo = (const float*)d_in[7];  const float* bo = (const float*)d_in[8];
    const float* W1 = (const float*)d_in[9];  const float* b1 = (const float*)d_in[10];
    const float* W2 = (const float*)d_in[11]; const float* b2 = (const float*)d_in[12];
    const float* g1 = (const float*)d_in[13]; const float* be1 = (const float*)d_in[14];
    const float* g2 = (const float*)d_in[15]; const float* be2 = (const float*)d_in[16];

    char* ws = (char*)d_ws;
    ushort* qm    = (ushort*)(ws + 0 * SZ);
    ushort* km    = (ushort*)(ws + 1 * SZ);
    ushort* v     = (ushort*)(ws + 2 * SZ);
    ushort* src16 = (ushort*)(ws + 3 * SZ);
    ushort* x16   = (ushort*)(ws + 4 * SZ);
    ushort* z16   = (ushort*)(ws + 5 * SZ);
    char*   tail  = ws + 6 * SZ;
    float*  kvp   = (float*)(tail);
    float*  ksump = (float*)(tail + 8388608);
    ushort* kvt   = (ushort*)(tail + 8519680);
    float*  ksum  = (float*)(tail + 8781824);
    float*  bqkv  = (float*)(tail + 8790016);
    ushort* wqkv  = (ushort*)(tail + 8796160);
    ushort* wot   = (ushort*)(tail + 10369024);
    ushort* w1t   = (ushort*)(tail + 10893312);
    ushort* w2t   = (ushort*)(tail + 12990464);
    ushort* attnE = km;
    ushort* y16   = v;
    ushort* hbuf  = (ushort*)(ws + 0);

    hipFuncSetAttribute((const void*)gemm256<3>, hipFuncAttributeMaxDynamicSharedMemorySize, SMEM256);

    // 1) converts
    conv_bf16<<<dim3((M * E / 4 + 255) / 256), 256, 0, stream>>>(src, src16, M * E / 4);
    wconv_t<<<dim3(E / 32, E / 32), 256, 0, stream>>>(Wq, wqkv, E, E);
    wconv_t<<<dim3(E / 32, E / 32), 256, 0, stream>>>(Wk, wqkv + 512 * 512, E, E);
    wconv_t<<<dim3(E / 32, E / 32), 256, 0, stream>>>(Wv, wqkv + 1024 * 512, E, E);
    wconv_t<<<dim3(E / 32, E / 32), 256, 0, stream>>>(Wo, wot, E, E);
    wconv_t<<<dim3(F / 32, E / 32), 256, 0, stream>>>(W1, w1t, E, F);
    wconv_t<<<dim3(E / 32, F / 32), 256, 0, stream>>>(W2, w2t, F, E);
    biascat<<<dim3(6), 256, 0, stream>>>(bq, bk, bv, bqkv);

    // 2) fused QKV GEMM (N=1536, Kt=16 -> gemm128; elu+1 on q,k segments)
    gemm128<4><<<dim3(12 * 256), 256, SMEM128, stream>>>(src16, wqkv, bqkv, nullptr, qm, M, 1536, E, 12);

    // 3) kv / ksum reduction
    kv_partial<<<dim3(16, 32), 256, 0, stream>>>(km, v, kvp, ksump, S);
    kv_reduce<<<dim3((32 * 4096 + 32 * 64 + 255) / 256), 256, 0, stream>>>(kvp, ksump, kvt, ksum);

    // 4) attention combine (MFMA)
    attn_mfma<<<dim3(4, M / 128), 256, 0, stream>>>(qm, kvt, ksum, attnE, S);

    // 5) output proj + bf16 residual (Kt=16 -> gemm128), then LN -> x16
    gemm128<3><<<dim3(4 * 256), 256, SMEM128, stream>>>(attnE, wot, bo, src16, y16, M, E, E, 4);
    ln_bf16<0><<<dim3(M / 4), 256, 0, stream>>>(y16, g1, be1, x16, M);

    // 6) FFN: W1 (Kt=16 -> gemm128), W2 (Kt=64 -> gemm256)
    gemm128<2><<<dim3(16 * 256), 256, SMEM128, stream>>>(x16, w1t, b1, nullptr, hbuf, M, F, E, 16);
    gemm256<3><<<dim3(2 * 128), 512, SMEM256, stream>>>(hbuf, w2t, b2, x16, z16, M, E, F, 2);
    ln_bf16<1><<<dim3(M / 4), 256, 0, stream>>>(z16, g2, be2, (float*)d_out, M);
}

// Round 9
// 379.367 us; speedup vs baseline: 5.9112x; 1.0379x over previous
//
#include <hip/hip_runtime.h>
#include <hip/hip_bf16.h>

typedef __attribute__((ext_vector_type(8))) short bf16x8;
typedef __attribute__((ext_vector_type(4))) float f32x4;

__device__ inline ushort f2bf(float f) {
    uint u = __float_as_uint(f);
    u += 0x7fff + ((u >> 16) & 1);
    return (ushort)(u >> 16);
}
__device__ inline float bf2f(ushort h) {
    return __uint_as_float(((uint)h) << 16);
}

__device__ inline void gload16(const void* g, void* lds) {
    __builtin_amdgcn_global_load_lds(
        (const __attribute__((address_space(1))) void*)g,
        (__attribute__((address_space(3))) void*)lds, 16, 0, 0);
}

// ---------------- converts ----------------
__global__ void conv_bf16(const float* __restrict__ in, ushort* __restrict__ out, int n4) {
    int i = blockIdx.x * 256 + threadIdx.x;
    if (i >= n4) return;
    float4 a = ((const float4*)in)[i];
    ushort4 o;
    o.x = f2bf(a.x); o.y = f2bf(a.y); o.z = f2bf(a.z); o.w = f2bf(a.w);
    ((ushort4*)out)[i] = o;
}

// in: fp32 [K,N] -> out: bf16 [N,K]
__global__ void wconv_t(const float* __restrict__ in, ushort* __restrict__ out, int K, int N) {
    __shared__ float tile[32][33];
    int kb = blockIdx.y * 32, nb = blockIdx.x * 32;
    int tx = threadIdx.x & 31, ty = threadIdx.x >> 5;  // 32 x 8
#pragma unroll
    for (int i = 0; i < 4; i++)
        tile[ty + i * 8][tx] = in[(size_t)(kb + ty + i * 8) * N + nb + tx];
    __syncthreads();
#pragma unroll
    for (int i = 0; i < 4; i++) {
        int n = nb + ty + i * 8, k = kb + tx;
        out[(size_t)n * K + k] = f2bf(tile[tx][ty + i * 8]);
    }
}

__global__ void biascat(const float* __restrict__ a, const float* __restrict__ b,
                        const float* __restrict__ c, float* __restrict__ o) {
    int i = blockIdx.x * 256 + threadIdx.x;
    if (i < 512) o[i] = a[i];
    else if (i < 1024) o[i] = b[i - 512];
    else if (i < 1536) o[i] = c[i - 1024];
}

// ============ 256x256 persistent multi-tile GEMM: C = A[M,K] @ Bt[N,K]^T + bias ============
// r6-proven skeleton: (512,2), 8 waves 2Mx4N, BK=32, 4-buffer 128KB LDS, 3-deep
// prefetch, counted vmcnt, phased ds_read/MFMA.  NEW: each block processes NT
// consecutive bx tiles (same by) as ONE continuous K-pipeline (global stage index g
// over NT*Kt tiles); per-tile epilogues run between pipeline iterations, overlapped
// with the in-flight stages of the next tile. Prologue paid once per block, not NT x.
// vmcnt correctness with epilogue stores in the queue: waitcnt retirement is
// IN-ORDER, so "<=N outstanding" guarantees everything older than the newest N ops
// retired; staged loads for tile g are always older than the newest 8 at the ladder
// points, so the r6 argument carries over (stores merely make the wait conservative).
// WAR safety: stage(g+3) writes buf[(g-1)&3]; all waves drained lgkmcnt(0) on their
// buf[g-1] reads before iteration g-1's phase-2 barrier, which precedes iteration g.
// EPI: 2 = relu bf16; 3 = bf16 residual add; 4 = fused QKV (seg<2: elu+1) -> [3][M][512]
template <int EPI, int NT>
__global__ __launch_bounds__(512, 2) void gemm256(
    const ushort* __restrict__ A, const ushort* __restrict__ Bt,
    const float* __restrict__ bias, const ushort* __restrict__ res16,
    ushort* __restrict__ out16, int M, int N, int K, int nbxg) {
    extern __shared__ char smem[];  // 4 * 32768
    const int t = threadIdx.x;
    const int w = t >> 6, l = t & 63;
    const int wr = w >> 2, wc = w & 3;
    // XCD-chunked bijective swizzle (grid divisible by 8)
    const int nwg = gridDim.x;
    const int cpx = nwg >> 3;
    const int swz = (blockIdx.x & 7) * cpx + (blockIdx.x >> 3);
    const int bxg = swz % nbxg, by = swz / nbxg;
    const int bx0 = bxg * NT;

    // staging source: thread t covers storage bytes t*16 of each 8KB quarter.
    // storage row = t>>2, chunk = t&3; source logical chunk = (t&3)^((row>>1)&3)
    const int sc = (t & 3) ^ ((t >> 3) & 3);
    const ushort* gA0 = A + (size_t)(by * 256 + (t >> 2)) * K + sc * 8;
    const ushort* gA1 = gA0 + (size_t)128 * K;
    const ushort* sB0 = Bt + (size_t)(bx0 * 256 + (t >> 2)) * K + sc * 8;
    const ushort* sB1 = sB0 + (size_t)128 * K;

    const int Kt = K >> 5;
    const int TOT = NT * Kt;
    int stg_kt = 0, stg_g = 0;  // staging cursor (next stage to issue)

    auto stage_h0 = [&]() {
        char* Lb = smem + (stg_g & 3) * 32768 + (w << 10);
        gload16(gA0 + stg_kt * 32, Lb);
        gload16(sB0 + stg_kt * 32, Lb + 16384);
    };
    auto stage_h1 = [&]() {
        char* Lb = smem + (stg_g & 3) * 32768 + (w << 10);
        gload16(gA1 + stg_kt * 32, Lb + 8192);
        gload16(sB1 + stg_kt * 32, Lb + 24576);
        ++stg_g;
        if (++stg_kt == Kt) {  // advance B to next bx tile
            stg_kt = 0;
            sB0 += (size_t)256 * K;
            sB1 += (size_t)256 * K;
        }
    };

    f32x4 acc[8][4] = {};

    // ds_read offsets (constant per thread): logical (row, kchunk=l>>4) -> swizzled chunk
    const int R0a = wr * 128 + (l & 15);
    const int offA = R0a * 64 + (((l >> 4) ^ ((R0a >> 1) & 3)) << 4);
    const int R0b = wc * 64 + (l & 15);
    const int offB = 16384 + R0b * 64 + (((l >> 4) ^ ((R0b >> 1) & 3)) << 4);

    // prologue: 3 stages in flight (12 loads)
    stage_h0(); stage_h1();
    stage_h0(); stage_h1();
    stage_h0(); stage_h1();

    int g = 0;
    for (int j = 0; j < NT; ++j) {
#pragma unroll 1
        for (int kt = 0; kt < Kt; ++kt, ++g) {
            const int rem = TOT - 1 - g;
            if (rem >= 2)      asm volatile("s_waitcnt vmcnt(8)" ::: "memory");
            else if (rem == 1) asm volatile("s_waitcnt vmcnt(4)" ::: "memory");
            else               asm volatile("s_waitcnt vmcnt(0)" ::: "memory");
            __builtin_amdgcn_s_barrier();          // stage(g) visible to all waves
            __builtin_amdgcn_sched_barrier(0);

            const char* bufp = smem + (g & 3) * 32768;
            bf16x8 a[8], b[4];
            // ---- phase 1: issue reads (b0-3, a0-3) + half-stage, barrier, consume
            b[0] = *(const bf16x8*)(bufp + offB);
            b[1] = *(const bf16x8*)(bufp + offB + 1024);
            b[2] = *(const bf16x8*)(bufp + offB + 2048);
            b[3] = *(const bf16x8*)(bufp + offB + 3072);
            a[0] = *(const bf16x8*)(bufp + offA);
            a[1] = *(const bf16x8*)(bufp + offA + 1024);
            a[2] = *(const bf16x8*)(bufp + offA + 2048);
            a[3] = *(const bf16x8*)(bufp + offA + 3072);
            if (g + 3 < TOT) stage_h0();
            __builtin_amdgcn_sched_barrier(0);
            __builtin_amdgcn_s_barrier();
            asm volatile("s_waitcnt lgkmcnt(0)" ::: "memory");
            __builtin_amdgcn_sched_barrier(0);
            __builtin_amdgcn_s_setprio(1);
#pragma unroll
            for (int m = 0; m < 4; m++)
#pragma unroll
                for (int n = 0; n < 4; n++)
                    acc[m][n] = __builtin_amdgcn_mfma_f32_16x16x32_bf16(a[m], b[n], acc[m][n], 0, 0, 0);
            __builtin_amdgcn_s_setprio(0);
            __builtin_amdgcn_sched_barrier(0);
            // ---- phase 2: issue reads (a4-7) + half-stage, barrier, consume
            a[4] = *(const bf16x8*)(bufp + offA + 4096);
            a[5] = *(const bf16x8*)(bufp + offA + 5120);
            a[6] = *(const bf16x8*)(bufp + offA + 6144);
            a[7] = *(const bf16x8*)(bufp + offA + 7168);
            if (g + 3 < TOT) stage_h1();
            __builtin_amdgcn_sched_barrier(0);
            __builtin_amdgcn_s_barrier();
            asm volatile("s_waitcnt lgkmcnt(0)" ::: "memory");
            __builtin_amdgcn_sched_barrier(0);
            __builtin_amdgcn_s_setprio(1);
#pragma unroll
            for (int m = 4; m < 8; m++)
#pragma unroll
                for (int n = 0; n < 4; n++)
                    acc[m][n] = __builtin_amdgcn_mfma_f32_16x16x32_bf16(a[m], b[n], acc[m][n], 0, 0, 0);
            __builtin_amdgcn_s_setprio(0);
            __builtin_amdgcn_sched_barrier(0);
        }

        // ---- epilogue for tile bx = bx0 + j (no LDS use; overlaps next tile's
        // in-flight stages). n INNERMOST for full-128B-sector store merge.
        {
            const int bx = bx0 + j;
            const int row0 = by * 256 + wr * 128 + ((l >> 4) << 2);
            const int col0 = bx * 256 + wc * 64 + (l & 15);
            const int seg = bx >> 1;  // EPI4: 512-col segment (256-tile never straddles)
            const size_t segoff = (size_t)seg * M * 512;
            const int c511 = col0 & 511;
            float bv[4];
#pragma unroll
            for (int n = 0; n < 4; n++) bv[n] = bias[col0 + n * 16];
#pragma unroll
            for (int m = 0; m < 8; m++) {
#pragma unroll
                for (int r = 0; r < 4; r++) {
                    const int row = row0 + m * 16 + r;
                    const size_t base = (size_t)row * N + col0;
#pragma unroll
                    for (int n = 0; n < 4; n++) {
                        float vv = acc[m][n][r] + bv[n];
                        if constexpr (EPI == 2) {
                            vv = vv > 0.f ? vv : 0.f;
                            out16[base + n * 16] = f2bf(vv);
                        } else if constexpr (EPI == 3) {
                            vv += bf2f(res16[base + n * 16]);
                            out16[base + n * 16] = f2bf(vv);
                        } else if constexpr (EPI == 4) {
                            if (seg < 2) vv = vv > 0.f ? vv + 1.f : __expf(vv);
                            out16[segoff + (size_t)row * 512 + c511 + n * 16] = f2bf(vv);
                        } else {
                            out16[base + n * 16] = f2bf(vv);
                        }
                    }
                }
            }
            if (j + 1 < NT) {
#pragma unroll
                for (int m = 0; m < 8; m++)
#pragma unroll
                    for (int n = 0; n < 4; n++)
                        acc[m][n] = (f32x4){0.f, 0.f, 0.f, 0.f};
            }
        }
    }
}

// ---------------- kv partial reduction ----------------
__global__ __launch_bounds__(256) void kv_partial(
    const ushort* __restrict__ km, const ushort* __restrict__ v,
    float* __restrict__ kvp, float* __restrict__ ksump, int S) {
    __shared__ ushort kms[32 * 64];
    __shared__ ushort vs[32 * 64];
    const int t = threadIdx.x;
    const int bh = blockIdx.y, b = bh >> 3, h = bh & 7;
    const int d0 = (t >> 4) * 4, e0 = (t & 15) * 4;
    float acc[4][4] = {};
    float ks = 0.f;
    const int s_base = blockIdx.x * 512;
    const int r = t >> 3, c8 = (t & 7) * 8;
    for (int s0 = 0; s0 < 512; s0 += 32) {
        size_t grow = ((size_t)b * S + s_base + s0 + r) * 512 + h * 64 + c8;
        *(uint4*)&kms[r * 64 + c8] = *(const uint4*)&km[grow];
        *(uint4*)&vs[r * 64 + c8] = *(const uint4*)&v[grow];
        __syncthreads();
#pragma unroll 4
        for (int s = 0; s < 32; ++s) {
            ushort4 ka = *(const ushort4*)&kms[s * 64 + d0];
            ushort4 vb = *(const ushort4*)&vs[s * 64 + e0];
            float a0 = bf2f(ka.x), a1 = bf2f(ka.y), a2 = bf2f(ka.z), a3 = bf2f(ka.w);
            float b0 = bf2f(vb.x), b1 = bf2f(vb.y), b2 = bf2f(vb.z), b3 = bf2f(vb.w);
            acc[0][0] += a0 * b0; acc[0][1] += a0 * b1; acc[0][2] += a0 * b2; acc[0][3] += a0 * b3;
            acc[1][0] += a1 * b0; acc[1][1] += a1 * b1; acc[1][2] += a1 * b2; acc[1][3] += a1 * b3;
            acc[2][0] += a2 * b0; acc[2][1] += a2 * b1; acc[2][2] += a2 * b2; acc[2][3] += a2 * b3;
            acc[3][0] += a3 * b0; acc[3][1] += a3 * b1; acc[3][2] += a3 * b2; acc[3][3] += a3 * b3;
            if (t < 64) ks += bf2f(kms[s * 64 + t]);
        }
        __syncthreads();
    }
    float* dst = kvp + ((size_t)bh * 16 + blockIdx.x) * 4096;
#pragma unroll
    for (int i = 0; i < 4; i++)
#pragma unroll
        for (int j = 0; j < 4; j++)
            dst[(d0 + i) * 64 + e0 + j] = acc[i][j];
    if (t < 64) ksump[((size_t)bh * 16 + blockIdx.x) * 64 + t] = ks;
}

// reduce partials; kv emitted TRANSPOSED per head as bf16: kvt[bh][e][d]
__global__ void kv_reduce(const float* __restrict__ kvp, const float* __restrict__ ksump,
                          ushort* __restrict__ kvt, float* __restrict__ ksum) {
    int i = blockIdx.x * 256 + threadIdx.x;
    if (i < 32 * 4096) {
        int bh = i >> 12, de = i & 4095;
        int d = de >> 6, e = de & 63;
        float s = 0.f;
#pragma unroll
        for (int c = 0; c < 16; ++c) s += kvp[((size_t)bh * 16 + c) * 4096 + de];
        kvt[(size_t)bh * 4096 + e * 64 + d] = f2bf(s);
    } else {
        int j = i - 32 * 4096;
        if (j < 32 * 64) {
            int bh = j >> 6, d = j & 63;
            float s = 0.f;
#pragma unroll
            for (int c = 0; c < 16; ++c) s += ksump[((size_t)bh * 16 + c) * 64 + d];
            ksum[j] = s;
        }
    }
}

// ---------------- attn via MFMA: per (b,h) attn = qm[S,64] @ kv[64,64], * z ----------------
__global__ __launch_bounds__(256) void attn_mfma(
    const ushort* __restrict__ qm, const ushort* __restrict__ kvt,
    const float* __restrict__ ksum, ushort* __restrict__ attnE, int S) {
    __shared__ ushort As[128 * 128];
    __shared__ ushort Bs[128 * 64];
    __shared__ float zbuf[128][2];
    __shared__ float ks2[128];
    const int t = threadIdx.x, w = t >> 6, l = t & 63;
    const int cx = blockIdx.x, by = blockIdx.y;
    const int b = (by * 128) / S;
    const int h0 = cx * 2;
    const size_t arow0 = (size_t)(by * 128) * 512 + cx * 128;

#pragma unroll
    for (int rd = 0; rd < 8; ++rd) {
        const ushort* g = qm + arow0 + (size_t)(rd * 16 + w * 4 + (l >> 4)) * 512 + (l & 15) * 8;
        gload16(g, (char*)As + rd * 4096 + w * 1024);
    }
    const ushort* kvbase = kvt + (size_t)(b * 8 + h0) * 4096;
#pragma unroll
    for (int rd = 0; rd < 4; ++rd) {
        const ushort* g = kvbase + (rd * 32 + w * 8 + (l >> 3)) * 64 + (l & 7) * 8;
        gload16(g, (char*)Bs + rd * 4096 + w * 1024);
    }
    if (t < 128) ks2[t] = ksum[(b * 8 + h0) * 64 + t];
    __syncthreads();

    {
        const int r = t >> 1, hh = t & 1;
        float den = 0.f;
#pragma unroll
        for (int d0 = 0; d0 < 64; d0 += 8) {
            bf16x8 qv = *(const bf16x8*)&As[r * 128 + hh * 64 + d0];
#pragma unroll
            for (int j = 0; j < 8; j++) den += bf2f((ushort)qv[j]) * ks2[hh * 64 + d0 + j];
        }
        zbuf[r][hh] = 1.0f / (den + 1e-6f);
    }

    const int wr = w >> 1, wc = w & 1;
    const int ar = wr * 64 + (l & 15);
    const int br = wc * 64 + (l & 15);
    const int ko = (l >> 4) * 8;
    f32x4 acc[4][4] = {};
#pragma unroll
    for (int ks_ = 0; ks_ < 2; ++ks_) {
        bf16x8 a[4], bb[4];
#pragma unroll
        for (int m = 0; m < 4; m++)
            a[m] = *(const bf16x8*)&As[(ar + m * 16) * 128 + wc * 64 + ks_ * 32 + ko];
#pragma unroll
        for (int n = 0; n < 4; n++)
            bb[n] = *(const bf16x8*)&Bs[(br + n * 16) * 64 + ks_ * 32 + ko];
#pragma unroll
        for (int m = 0; m < 4; m++)
#pragma unroll
            for (int n = 0; n < 4; n++)
                acc[m][n] = __builtin_amdgcn_mfma_f32_16x16x32_bf16(a[m], bb[n], acc[m][n], 0, 0, 0);
    }
    __syncthreads();

    const int row0l = wr * 64 + ((l >> 4) << 2);
    ushort* outbase = attnE + (size_t)(by * 128) * 512 + cx * 128;
#pragma unroll
    for (int n = 0; n < 4; n++) {
#pragma unroll
        for (int m = 0; m < 4; m++) {
#pragma unroll
            for (int r = 0; r < 4; r++) {
                int rl = row0l + m * 16 + r;
                float z = zbuf[rl][wc];
                outbase[(size_t)rl * 512 + wc * 64 + n * 16 + (l & 15)] = f2bf(acc[m][n][r] * z);
            }
        }
    }
}

// ---------------- LayerNorm over bf16 input ----------------
template <int OUT32>
__global__ __launch_bounds__(256) void ln_bf16(
    const ushort* __restrict__ in, const float* __restrict__ g, const float* __restrict__ be,
    void* __restrict__ outp, int Mrows) {
    const int w = threadIdx.x >> 6, l = threadIdx.x & 63;
    const int row = blockIdx.x * 4 + w;
    if (row >= Mrows) return;
    const ushort* rp = in + (size_t)row * 512;
    uint4 u = *(const uint4*)&rp[l * 8];
    float x[8];
    x[0] = bf2f((ushort)(u.x & 0xffff)); x[1] = bf2f((ushort)(u.x >> 16));
    x[2] = bf2f((ushort)(u.y & 0xffff)); x[3] = bf2f((ushort)(u.y >> 16));
    x[4] = bf2f((ushort)(u.z & 0xffff)); x[5] = bf2f((ushort)(u.z >> 16));
    x[6] = bf2f((ushort)(u.w & 0xffff)); x[7] = bf2f((ushort)(u.w >> 16));
    float s = 0.f, ss = 0.f;
#pragma unroll
    for (int j = 0; j < 8; j++) { s += x[j]; ss += x[j] * x[j]; }
#pragma unroll
    for (int o = 1; o < 64; o <<= 1) {
        s += __shfl_xor(s, o, 64);
        ss += __shfl_xor(ss, o, 64);
    }
    float mean = s * (1.f / 512.f);
    float var = ss * (1.f / 512.f) - mean * mean;
    float rstd = rsqrtf(var + 1e-5f);
    float4 g0 = *(const float4*)&g[l * 8], g1v = *(const float4*)&g[l * 8 + 4];
    float4 b0 = *(const float4*)&be[l * 8], b1v = *(const float4*)&be[l * 8 + 4];
    float o0[8];
    o0[0] = (x[0] - mean) * rstd * g0.x + b0.x;
    o0[1] = (x[1] - mean) * rstd * g0.y + b0.y;
    o0[2] = (x[2] - mean) * rstd * g0.z + b0.z;
    o0[3] = (x[3] - mean) * rstd * g0.w + b0.w;
    o0[4] = (x[4] - mean) * rstd * g1v.x + b1v.x;
    o0[5] = (x[5] - mean) * rstd * g1v.y + b1v.y;
    o0[6] = (x[6] - mean) * rstd * g1v.z + b1v.z;
    o0[7] = (x[7] - mean) * rstd * g1v.w + b1v.w;
    if constexpr (OUT32) {
        float* op = (float*)outp + (size_t)row * 512;
        *(float4*)&op[l * 8] = make_float4(o0[0], o0[1], o0[2], o0[3]);
        *(float4*)&op[l * 8 + 4] = make_float4(o0[4], o0[5], o0[6], o0[7]);
    } else {
        ushort* op = (ushort*)outp + (size_t)row * 512;
        ushort4 u0, u1;
        u0.x = f2bf(o0[0]); u0.y = f2bf(o0[1]); u0.z = f2bf(o0[2]); u0.w = f2bf(o0[3]);
        u1.x = f2bf(o0[4]); u1.y = f2bf(o0[5]); u1.z = f2bf(o0[6]); u1.w = f2bf(o0[7]);
        *(ushort4*)&op[l * 8] = u0;
        *(ushort4*)&op[l * 8 + 4] = u1;
    }
}

extern "C" void kernel_launch(void* const* d_in, const int* in_sizes, int n_in,
                              void* d_out, int out_size, void* d_ws, size_t ws_size,
                              hipStream_t stream) {
    const int B = 4, S = 8192, E = 512, F = 2048;
    const int M = B * S;  // 32768
    const size_t SZ = (size_t)M * E * 2;  // 32 MiB
    const int SMEM = 131072;

    const float* src = (const float*)d_in[0];
    const float* Wq = (const float*)d_in[1];  const float* bq = (const float*)d_in[2];
    const float* Wk = (const float*)d_in[3];  const float* bk = (const float*)d_in[4];
    const float* Wv = (const float*)d_in[5];  const float* bv = (const float*)d_in[6];
    const float* Wo = (const float*)d_in[7];  const float* bo = (const float*)d_in[8];
    const float* W1 = (const float*)d_in[9];  const float* b1 = (const float*)d_in[10];
    const float* W2 = (const float*)d_in[11]; const float* b2 = (const float*)d_in[12];
    const float* g1 = (const float*)d_in[13]; const float* be1 = (const float*)d_in[14];
    const float* g2 = (const float*)d_in[15]; const float* be2 = (const float*)d_in[16];

    char* ws = (char*)d_ws;
    ushort* qm    = (ushort*)(ws + 0 * SZ);
    ushort* km    = (ushort*)(ws + 1 * SZ);
    ushort* v     = (ushort*)(ws + 2 * SZ);
    ushort* src16 = (ushort*)(ws + 3 * SZ);
    ushort* x16   = (ushort*)(ws + 4 * SZ);
    ushort* z16   = (ushort*)(ws + 5 * SZ);
    char*   tail  = ws + 6 * SZ;
    float*  kvp   = (float*)(tail);
    float*  ksump = (float*)(tail + 8388608);
    ushort* kvt   = (ushort*)(tail + 8519680);
    float*  ksum  = (float*)(tail + 8781824);
    float*  bqkv  = (float*)(tail + 8790016);
    ushort* wqkv  = (ushort*)(tail + 8796160);
    ushort* wot   = (ushort*)(tail + 10369024);
    ushort* w1t   = (ushort*)(tail + 10893312);
    ushort* w2t   = (ushort*)(tail + 12990464);
    ushort* attnE = km;
    ushort* y16   = v;
    ushort* hbuf  = (ushort*)(ws + 0);

    hipFuncSetAttribute((const void*)gemm256<4, 3>, hipFuncAttributeMaxDynamicSharedMemorySize, SMEM);
    hipFuncSetAttribute((const void*)gemm256<3, 1>, hipFuncAttributeMaxDynamicSharedMemorySize, SMEM);
    hipFuncSetAttribute((const void*)gemm256<2, 4>, hipFuncAttributeMaxDynamicSharedMemorySize, SMEM);

    // 1) converts
    conv_bf16<<<dim3((M * E / 4 + 255) / 256), 256, 0, stream>>>(src, src16, M * E / 4);
    wconv_t<<<dim3(E / 32, E / 32), 256, 0, stream>>>(Wq, wqkv, E, E);
    wconv_t<<<dim3(E / 32, E / 32), 256, 0, stream>>>(Wk, wqkv + 512 * 512, E, E);
    wconv_t<<<dim3(E / 32, E / 32), 256, 0, stream>>>(Wv, wqkv + 1024 * 512, E, E);
    wconv_t<<<dim3(E / 32, E / 32), 256, 0, stream>>>(Wo, wot, E, E);
    wconv_t<<<dim3(F / 32, E / 32), 256, 0, stream>>>(W1, w1t, E, F);
    wconv_t<<<dim3(E / 32, F / 32), 256, 0, stream>>>(W2, w2t, F, E);
    biascat<<<dim3(6), 256, 0, stream>>>(bq, bk, bv, bqkv);

    // 2) fused QKV GEMM (N=1536, NT=3 -> 256 blocks; elu+1 on q,k segments)
    gemm256<4, 3><<<dim3(2 * 128), 512, SMEM, stream>>>(src16, wqkv, bqkv, nullptr, qm, M, 1536, E, 2);

    // 3) kv / ksum reduction
    kv_partial<<<dim3(16, 32), 256, 0, stream>>>(km, v, kvp, ksump, S);
    kv_reduce<<<dim3((32 * 4096 + 32 * 64 + 255) / 256), 256, 0, stream>>>(kvp, ksump, kvt, ksum);

    // 4) attention combine (MFMA)
    attn_mfma<<<dim3(4, M / 128), 256, 0, stream>>>(qm, kvt, ksum, attnE, S);

    // 5) output proj + bf16 residual, then LN -> x16
    gemm256<3, 1><<<dim3(2 * 128), 512, SMEM, stream>>>(attnE, wot, bo, src16, y16, M, E, E, 2);
    ln_bf16<0><<<dim3(M / 4), 256, 0, stream>>>(y16, g1, be1, x16, M);

    // 6) FFN: W1 (N=2048, NT=4 -> 256 blocks), W2 (Kt=64, NT=1)
    gemm256<2, 4><<<dim3(2 * 128), 512, SMEM, stream>>>(x16, w1t, b1, nullptr, hbuf, M, F, E, 2);
    gemm256<3, 1><<<dim3(2 * 128), 512, SMEM, stream>>>(hbuf, w2t, b2, x16, z16, M, E, F, 2);
    ln_bf16<1><<<dim3(M / 4), 256, 0, stream>>>(z16, g2, be2, (float*)d_out, M);
}

// Round 10
// 364.799 us; speedup vs baseline: 6.1472x; 1.0399x over previous
//
#include <hip/hip_runtime.h>
#include <hip/hip_bf16.h>

typedef __attribute__((ext_vector_type(8))) short bf16x8;
typedef __attribute__((ext_vector_type(4))) float f32x4;

__device__ inline ushort f2bf(float f) {
    uint u = __float_as_uint(f);
    u += 0x7fff + ((u >> 16) & 1);
    return (ushort)(u >> 16);
}
__device__ inline float bf2f(ushort h) {
    return __uint_as_float(((uint)h) << 16);
}

__device__ inline void gload16(const void* g, void* lds) {
    __builtin_amdgcn_global_load_lds(
        (const __attribute__((address_space(1))) void*)g,
        (__attribute__((address_space(3))) void*)lds, 16, 0, 0);
}

// ---------------- merged prep: src->bf16, 6 weight transpose-converts, bias concat ----------------
// one dispatch replaces 8 small serial kernels. Branch is block-uniform.
__global__ __launch_bounds__(256) void prep(
    const float* __restrict__ src, ushort* __restrict__ src16,
    const float* __restrict__ Wq, const float* __restrict__ Wk,
    const float* __restrict__ Wv, const float* __restrict__ Wo,
    const float* __restrict__ W1, const float* __restrict__ W2,
    ushort* __restrict__ wqkv, ushort* __restrict__ wot,
    ushort* __restrict__ w1t, ushort* __restrict__ w2t,
    const float* __restrict__ bq, const float* __restrict__ bk,
    const float* __restrict__ bv, float* __restrict__ bqkv) {
    __shared__ float tile[32][33];
    int bid = blockIdx.x;
    const int t = threadIdx.x;
    if (bid < 16384) {  // src fp32 -> bf16 (M*E/4 = 4194304 float4s)
        int i = bid * 256 + t;
        float4 a = ((const float4*)src)[i];
        ushort4 o;
        o.x = f2bf(a.x); o.y = f2bf(a.y); o.z = f2bf(a.z); o.w = f2bf(a.w);
        ((ushort4*)src16)[i] = o;
        return;
    }
    bid -= 16384;
    const float* in; ushort* out; int Kd, Nd;
    if (bid < 1024) {  // Wq,Wk,Wv,Wo: 256 blocks each
        int m = bid >> 8;
        in = (m == 0) ? Wq : (m == 1) ? Wk : (m == 2) ? Wv : Wo;
        out = (m == 3) ? wot : (wqkv + m * 512 * 512);
        Kd = 512; Nd = 512; bid &= 255;
    } else if (bid < 2048) { in = W1; out = w1t; Kd = 512; Nd = 2048; bid -= 1024; }
    else if (bid < 3072) { in = W2; out = w2t; Kd = 2048; Nd = 512; bid -= 2048; }
    else {  // bias concat: 6 blocks
        int i = (bid - 3072) * 256 + t;
        if (i < 512) bqkv[i] = bq[i];
        else if (i < 1024) bqkv[i] = bk[i - 512];
        else if (i < 1536) bqkv[i] = bv[i - 1024];
        return;
    }
    const int nx = Nd / 32;
    const int nbase = (bid % nx) * 32, kb = (bid / nx) * 32;
    const int tx = t & 31, ty = t >> 5;
#pragma unroll
    for (int i = 0; i < 4; i++)
        tile[ty + i * 8][tx] = in[(size_t)(kb + ty + i * 8) * Nd + nbase + tx];
    __syncthreads();
#pragma unroll
    for (int i = 0; i < 4; i++) {
        int n = nbase + ty + i * 8, k = kb + tx;
        out[(size_t)n * Kd + k] = f2bf(tile[tx][ty + i * 8]);
    }
}

// ============ 256x256 persistent GEMM, 1-barrier compiler-scheduled K-loop ============
// (512,2), 8 waves 2Mx4N, BK=32, 4-buffer 128KB, 3-deep prefetch, counted vmcnt.
// NEW: ONE barrier per K-tile; no explicit lgkmcnt drains -- hipcc inserts counted
// lgkmcnt between each ds_read and its dependent MFMA (m97-verified behavior), so
// in-wave read/MFMA overlap + cross-wave skew replace the 3-barrier lockstep.
// WAR safety (4-buffer): stage(g+3) writes buf[(g-1)&3]. Every wave's reads of
// buf[g-1] are CONSUMED (auto-lgkm before MFMA use) before it reaches tile-g's top
// barrier; stage(g+3) is issued after that barrier -> no overwrite race.
// vmcnt ladder: issued-through at tile-g top = stage g+2 -> allow 8 outstanding
// (stages g+1,g+2); rem==1 -> 4; rem==0 -> 0. Epilogue stores (NT>1) pollute the
// queue only at tile-group boundaries: the next top-wait then over-drains once
// (~stores' L2 latency), negligible per block.
// GB=0: persist over bx (B advances per tile); GB=1: persist over by (A advances).
// EPI: 2 = relu bf16; 3 = bf16 residual add; 4 = fused QKV (seg<2: elu+1) -> [3][M][512]
template <int EPI, int NT, int GB>
__global__ __launch_bounds__(512, 2) void gemm256(
    const ushort* __restrict__ A, const ushort* __restrict__ Bt,
    const float* __restrict__ bias, const ushort* __restrict__ res16,
    ushort* __restrict__ out16, int M, int N, int K, int nb1) {
    extern __shared__ char smem[];  // 4 * 32768
    const int t = threadIdx.x;
    const int w = t >> 6, l = t & 63;
    const int wr = w >> 2, wc = w & 3;
    // XCD-chunked bijective swizzle (grid divisible by 8)
    const int nwg = gridDim.x;
    const int cpx = nwg >> 3;
    const int swz = (blockIdx.x & 7) * cpx + (blockIdx.x >> 3);
    int bx0, by0;
    if (GB == 0) { bx0 = (swz % nb1) * NT; by0 = swz / nb1; }
    else         { bx0 = swz % nb1;        by0 = (swz / nb1) * NT; }

    // staging source: thread t covers storage bytes t*16 of each 8KB quarter.
    // storage row = t>>2, chunk = t&3; source logical chunk = (t&3)^((row>>1)&3)
    const int sc = (t & 3) ^ ((t >> 3) & 3);
    const ushort* gA0 = A + (size_t)(by0 * 256 + (t >> 2)) * K + sc * 8;
    const ushort* gA1 = gA0 + (size_t)128 * K;
    const ushort* gB0 = Bt + (size_t)(bx0 * 256 + (t >> 2)) * K + sc * 8;
    const ushort* gB1 = gB0 + (size_t)128 * K;

    const int Kt = K >> 5;
    const int TOT = NT * Kt;
    int stg_kt = 0, stg_g = 0;
    size_t stgA = 0, stgB = 0;  // per-tile advance: B (GB=0) or A (GB=1)

    auto stage_h0 = [&]() {
        char* Lb = smem + (stg_g & 3) * 32768 + (w << 10);
        gload16(gA0 + stgA + stg_kt * 32, Lb);
        gload16(gB0 + stgB + stg_kt * 32, Lb + 16384);
    };
    auto stage_h1 = [&]() {
        char* Lb = smem + (stg_g & 3) * 32768 + (w << 10);
        gload16(gA1 + stgA + stg_kt * 32, Lb + 8192);
        gload16(gB1 + stgB + stg_kt * 32, Lb + 24576);
        ++stg_g;
        if (++stg_kt == Kt) {
            stg_kt = 0;
            if (GB == 0) stgB += (size_t)256 * K;
            else         stgA += (size_t)256 * K;
        }
    };

    f32x4 acc[8][4] = {};

    // ds_read offsets: logical (row, kchunk=l>>4) -> swizzled chunk
    const int R0a = wr * 128 + (l & 15);
    const int offA = R0a * 64 + (((l >> 4) ^ ((R0a >> 1) & 3)) << 4);
    const int R0b = wc * 64 + (l & 15);
    const int offB = 16384 + R0b * 64 + (((l >> 4) ^ ((R0b >> 1) & 3)) << 4);

    // prologue: 3 stages in flight (12 loads)
    stage_h0(); stage_h1();
    stage_h0(); stage_h1();
    stage_h0(); stage_h1();

    int g = 0;
    for (int j = 0; j < NT; ++j) {
#pragma unroll 1
        for (int kt = 0; kt < Kt; ++kt, ++g) {
            const int rem = TOT - 1 - g;
            if (rem >= 2)      asm volatile("s_waitcnt vmcnt(8)" ::: "memory");
            else if (rem == 1) asm volatile("s_waitcnt vmcnt(4)" ::: "memory");
            else               asm volatile("s_waitcnt vmcnt(0)" ::: "memory");
            __builtin_amdgcn_s_barrier();      // stage(g) visible; prior-tile reads consumed
            __builtin_amdgcn_sched_barrier(0); // no reads hoisted above

            const char* bufp = smem + (g & 3) * 32768;
            if (g + 3 < TOT) { stage_h0(); stage_h1(); }  // long-latency first

            bf16x8 a[8], b[4];
#pragma unroll
            for (int n = 0; n < 4; n++) b[n] = *(const bf16x8*)(bufp + offB + n * 1024);
#pragma unroll
            for (int m = 0; m < 8; m++) a[m] = *(const bf16x8*)(bufp + offA + m * 1024);

            __builtin_amdgcn_s_setprio(1);
#pragma unroll
            for (int m = 0; m < 8; m++)
#pragma unroll
                for (int n = 0; n < 4; n++)
                    acc[m][n] = __builtin_amdgcn_mfma_f32_16x16x32_bf16(a[m], b[n], acc[m][n], 0, 0, 0);
            __builtin_amdgcn_s_setprio(0);
            __builtin_amdgcn_sched_barrier(0);  // keep MFMAs out of next iteration
        }

        // epilogue for tile j (no LDS; overlaps next tile's in-flight stages)
        {
            const int bx = (GB == 0) ? (bx0 + j) : bx0;
            const int by = (GB == 0) ? by0 : (by0 + j);
            const int row0 = by * 256 + wr * 128 + ((l >> 4) << 2);
            const int col0 = bx * 256 + wc * 64 + (l & 15);
            const int seg = bx >> 1;
            const size_t segoff = (size_t)seg * M * 512;
            const int c511 = col0 & 511;
            float bv[4];
#pragma unroll
            for (int n = 0; n < 4; n++) bv[n] = bias[col0 + n * 16];
#pragma unroll
            for (int m = 0; m < 8; m++) {
#pragma unroll
                for (int r = 0; r < 4; r++) {
                    const int row = row0 + m * 16 + r;
                    const size_t base = (size_t)row * N + col0;
#pragma unroll
                    for (int n = 0; n < 4; n++) {
                        float vv = acc[m][n][r] + bv[n];
                        if constexpr (EPI == 2) {
                            vv = vv > 0.f ? vv : 0.f;
                            out16[base + n * 16] = f2bf(vv);
                        } else if constexpr (EPI == 3) {
                            vv += bf2f(res16[base + n * 16]);
                            out16[base + n * 16] = f2bf(vv);
                        } else if constexpr (EPI == 4) {
                            if (seg < 2) vv = vv > 0.f ? vv + 1.f : __expf(vv);
                            out16[segoff + (size_t)row * 512 + c511 + n * 16] = f2bf(vv);
                        } else {
                            out16[base + n * 16] = f2bf(vv);
                        }
                    }
                }
            }
            if (j + 1 < NT) {
#pragma unroll
                for (int m = 0; m < 8; m++)
#pragma unroll
                    for (int n = 0; n < 4; n++)
                        acc[m][n] = (f32x4){0.f, 0.f, 0.f, 0.f};
            }
        }
    }
}

// ---------------- kv partial reduction ----------------
__global__ __launch_bounds__(256) void kv_partial(
    const ushort* __restrict__ km, const ushort* __restrict__ v,
    float* __restrict__ kvp, float* __restrict__ ksump, int S) {
    __shared__ ushort kms[32 * 64];
    __shared__ ushort vs[32 * 64];
    const int t = threadIdx.x;
    const int bh = blockIdx.y, b = bh >> 3, h = bh & 7;
    const int d0 = (t >> 4) * 4, e0 = (t & 15) * 4;
    float acc[4][4] = {};
    float ks = 0.f;
    const int s_base = blockIdx.x * 512;
    const int r = t >> 3, c8 = (t & 7) * 8;
    for (int s0 = 0; s0 < 512; s0 += 32) {
        size_t grow = ((size_t)b * S + s_base + s0 + r) * 512 + h * 64 + c8;
        *(uint4*)&kms[r * 64 + c8] = *(const uint4*)&km[grow];
        *(uint4*)&vs[r * 64 + c8] = *(const uint4*)&v[grow];
        __syncthreads();
#pragma unroll 4
        for (int s = 0; s < 32; ++s) {
            ushort4 ka = *(const ushort4*)&kms[s * 64 + d0];
            ushort4 vb = *(const ushort4*)&vs[s * 64 + e0];
            float a0 = bf2f(ka.x), a1 = bf2f(ka.y), a2 = bf2f(ka.z), a3 = bf2f(ka.w);
            float b0 = bf2f(vb.x), b1 = bf2f(vb.y), b2 = bf2f(vb.z), b3 = bf2f(vb.w);
            acc[0][0] += a0 * b0; acc[0][1] += a0 * b1; acc[0][2] += a0 * b2; acc[0][3] += a0 * b3;
            acc[1][0] += a1 * b0; acc[1][1] += a1 * b1; acc[1][2] += a1 * b2; acc[1][3] += a1 * b3;
            acc[2][0] += a2 * b0; acc[2][1] += a2 * b1; acc[2][2] += a2 * b2; acc[2][3] += a2 * b3;
            acc[3][0] += a3 * b0; acc[3][1] += a3 * b1; acc[3][2] += a3 * b2; acc[3][3] += a3 * b3;
            if (t < 64) ks += bf2f(kms[s * 64 + t]);
        }
        __syncthreads();
    }
    float* dst = kvp + ((size_t)bh * 16 + blockIdx.x) * 4096;
#pragma unroll
    for (int i = 0; i < 4; i++)
#pragma unroll
        for (int j = 0; j < 4; j++)
            dst[(d0 + i) * 64 + e0 + j] = acc[i][j];
    if (t < 64) ksump[((size_t)bh * 16 + blockIdx.x) * 64 + t] = ks;
}

// reduce partials; kv emitted TRANSPOSED per head as bf16: kvt[bh][e][d]
__global__ void kv_reduce(const float* __restrict__ kvp, const float* __restrict__ ksump,
                          ushort* __restrict__ kvt, float* __restrict__ ksum) {
    int i = blockIdx.x * 256 + threadIdx.x;
    if (i < 32 * 4096) {
        int bh = i >> 12, de = i & 4095;
        int d = de >> 6, e = de & 63;
        float s = 0.f;
#pragma unroll
        for (int c = 0; c < 16; ++c) s += kvp[((size_t)bh * 16 + c) * 4096 + de];
        kvt[(size_t)bh * 4096 + e * 64 + d] = f2bf(s);
    } else {
        int j = i - 32 * 4096;
        if (j < 32 * 64) {
            int bh = j >> 6, d = j & 63;
            float s = 0.f;
#pragma unroll
            for (int c = 0; c < 16; ++c) s += ksump[((size_t)bh * 16 + c) * 64 + d];
            ksum[j] = s;
        }
    }
}

// ---------------- attn via MFMA: per (b,h) attn = qm[S,64] @ kv[64,64], * z ----------------
__global__ __launch_bounds__(256) void attn_mfma(
    const ushort* __restrict__ qm, const ushort* __restrict__ kvt,
    const float* __restrict__ ksum, ushort* __restrict__ attnE, int S) {
    __shared__ ushort As[128 * 128];
    __shared__ ushort Bs[128 * 64];
    __shared__ float zbuf[128][2];
    __shared__ float ks2[128];
    const int t = threadIdx.x, w = t >> 6, l = t & 63;
    const int cx = blockIdx.x, by = blockIdx.y;
    const int b = (by * 128) / S;
    const int h0 = cx * 2;
    const size_t arow0 = (size_t)(by * 128) * 512 + cx * 128;

#pragma unroll
    for (int rd = 0; rd < 8; ++rd) {
        const ushort* g = qm + arow0 + (size_t)(rd * 16 + w * 4 + (l >> 4)) * 512 + (l & 15) * 8;
        gload16(g, (char*)As + rd * 4096 + w * 1024);
    }
    const ushort* kvbase = kvt + (size_t)(b * 8 + h0) * 4096;
#pragma unroll
    for (int rd = 0; rd < 4; ++rd) {
        const ushort* g = kvbase + (rd * 32 + w * 8 + (l >> 3)) * 64 + (l & 7) * 8;
        gload16(g, (char*)Bs + rd * 4096 + w * 1024);
    }
    if (t < 128) ks2[t] = ksum[(b * 8 + h0) * 64 + t];
    __syncthreads();

    {
        const int r = t >> 1, hh = t & 1;
        float den = 0.f;
#pragma unroll
        for (int d0 = 0; d0 < 64; d0 += 8) {
            bf16x8 qv = *(const bf16x8*)&As[r * 128 + hh * 64 + d0];
#pragma unroll
            for (int j = 0; j < 8; j++) den += bf2f((ushort)qv[j]) * ks2[hh * 64 + d0 + j];
        }
        zbuf[r][hh] = 1.0f / (den + 1e-6f);
    }

    const int wr = w >> 1, wc = w & 1;
    const int ar = wr * 64 + (l & 15);
    const int br = wc * 64 + (l & 15);
    const int ko = (l >> 4) * 8;
    f32x4 acc[4][4] = {};
#pragma unroll
    for (int ks_ = 0; ks_ < 2; ++ks_) {
        bf16x8 a[4], bb[4];
#pragma unroll
        for (int m = 0; m < 4; m++)
            a[m] = *(const bf16x8*)&As[(ar + m * 16) * 128 + wc * 64 + ks_ * 32 + ko];
#pragma unroll
        for (int n = 0; n < 4; n++)
            bb[n] = *(const bf16x8*)&Bs[(br + n * 16) * 64 + ks_ * 32 + ko];
#pragma unroll
        for (int m = 0; m < 4; m++)
#pragma unroll
            for (int n = 0; n < 4; n++)
                acc[m][n] = __builtin_amdgcn_mfma_f32_16x16x32_bf16(a[m], bb[n], acc[m][n], 0, 0, 0);
    }
    __syncthreads();

    const int row0l = wr * 64 + ((l >> 4) << 2);
    ushort* outbase = attnE + (size_t)(by * 128) * 512 + cx * 128;
#pragma unroll
    for (int n = 0; n < 4; n++) {
#pragma unroll
        for (int m = 0; m < 4; m++) {
#pragma unroll
            for (int r = 0; r < 4; r++) {
                int rl = row0l + m * 16 + r;
                float z = zbuf[rl][wc];
                outbase[(size_t)rl * 512 + wc * 64 + n * 16 + (l & 15)] = f2bf(acc[m][n][r] * z);
            }
        }
    }
}

// ---------------- LayerNorm over bf16 input ----------------
template <int OUT32>
__global__ __launch_bounds__(256) void ln_bf16(
    const ushort* __restrict__ in, const float* __restrict__ g, const float* __restrict__ be,
    void* __restrict__ outp, int Mrows) {
    const int w = threadIdx.x >> 6, l = threadIdx.x & 63;
    const int row = blockIdx.x * 4 + w;
    if (row >= Mrows) return;
    const ushort* rp = in + (size_t)row * 512;
    uint4 u = *(const uint4*)&rp[l * 8];
    float x[8];
    x[0] = bf2f((ushort)(u.x & 0xffff)); x[1] = bf2f((ushort)(u.x >> 16));
    x[2] = bf2f((ushort)(u.y & 0xffff)); x[3] = bf2f((ushort)(u.y >> 16));
    x[4] = bf2f((ushort)(u.z & 0xffff)); x[5] = bf2f((ushort)(u.z >> 16));
    x[6] = bf2f((ushort)(u.w & 0xffff)); x[7] = bf2f((ushort)(u.w >> 16));
    float s = 0.f, ss = 0.f;
#pragma unroll
    for (int j = 0; j < 8; j++) { s += x[j]; ss += x[j] * x[j]; }
#pragma unroll
    for (int o = 1; o < 64; o <<= 1) {
        s += __shfl_xor(s, o, 64);
        ss += __shfl_xor(ss, o, 64);
    }
    float mean = s * (1.f / 512.f);
    float var = ss * (1.f / 512.f) - mean * mean;
    float rstd = rsqrtf(var + 1e-5f);
    float4 g0 = *(const float4*)&g[l * 8], g1v = *(const float4*)&g[l * 8 + 4];
    float4 b0 = *(const float4*)&be[l * 8], b1v = *(const float4*)&be[l * 8 + 4];
    float o0[8];
    o0[0] = (x[0] - mean) * rstd * g0.x + b0.x;
    o0[1] = (x[1] - mean) * rstd * g0.y + b0.y;
    o0[2] = (x[2] - mean) * rstd * g0.z + b0.z;
    o0[3] = (x[3] - mean) * rstd * g0.w + b0.w;
    o0[4] = (x[4] - mean) * rstd * g1v.x + b1v.x;
    o0[5] = (x[5] - mean) * rstd * g1v.y + b1v.y;
    o0[6] = (x[6] - mean) * rstd * g1v.z + b1v.z;
    o0[7] = (x[7] - mean) * rstd * g1v.w + b1v.w;
    if constexpr (OUT32) {
        float* op = (float*)outp + (size_t)row * 512;
        *(float4*)&op[l * 8] = make_float4(o0[0], o0[1], o0[2], o0[3]);
        *(float4*)&op[l * 8 + 4] = make_float4(o0[4], o0[5], o0[6], o0[7]);
    } else {
        ushort* op = (ushort*)outp + (size_t)row * 512;
        ushort4 u0, u1;
        u0.x = f2bf(o0[0]); u0.y = f2bf(o0[1]); u0.z = f2bf(o0[2]); u0.w = f2bf(o0[3]);
        u1.x = f2bf(o0[4]); u1.y = f2bf(o0[5]); u1.z = f2bf(o0[6]); u1.w = f2bf(o0[7]);
        *(ushort4*)&op[l * 8] = u0;
        *(ushort4*)&op[l * 8 + 4] = u1;
    }
}

extern "C" void kernel_launch(void* const* d_in, const int* in_sizes, int n_in,
                              void* d_out, int out_size, void* d_ws, size_t ws_size,
                              hipStream_t stream) {
    const int B = 4, S = 8192, E = 512, F = 2048;
    const int M = B * S;  // 32768
    const size_t SZ = (size_t)M * E * 2;  // 32 MiB
    const int SMEM = 131072;

    const float* src = (const float*)d_in[0];
    const float* Wq = (const float*)d_in[1];  const float* bq = (const float*)d_in[2];
    const float* Wk = (const float*)d_in[3];  const float* bk = (const float*)d_in[4];
    const float* Wv = (const float*)d_in[5];  const float* bv = (const float*)d_in[6];
    const float* Wo = (const float*)d_in[7];  const float* bo = (const float*)d_in[8];
    const float* W1 = (const float*)d_in[9];  const float* b1 = (const float*)d_in[10];
    const float* W2 = (const float*)d_in[11]; const float* b2 = (const float*)d_in[12];
    const float* g1 = (const float*)d_in[13]; const float* be1 = (const float*)d_in[14];
    const float* g2 = (const float*)d_in[15]; const float* be2 = (const float*)d_in[16];

    char* ws = (char*)d_ws;
    ushort* qm    = (ushort*)(ws + 0 * SZ);
    ushort* km    = (ushort*)(ws + 1 * SZ);
    ushort* v     = (ushort*)(ws + 2 * SZ);
    ushort* src16 = (ushort*)(ws + 3 * SZ);
    ushort* x16   = (ushort*)(ws + 4 * SZ);
    ushort* z16   = (ushort*)(ws + 5 * SZ);
    char*   tail  = ws + 6 * SZ;
    float*  kvp   = (float*)(tail);
    float*  ksump = (float*)(tail + 8388608);
    ushort* kvt   = (ushort*)(tail + 8519680);
    float*  ksum  = (float*)(tail + 8781824);
    float*  bqkv  = (float*)(tail + 8790016);
    ushort* wqkv  = (ushort*)(tail + 8796160);
    ushort* wot   = (ushort*)(tail + 10369024);
    ushort* w1t   = (ushort*)(tail + 10893312);
    ushort* w2t   = (ushort*)(tail + 12990464);
    ushort* attnE = km;
    ushort* y16   = v;
    ushort* hbuf  = (ushort*)(ws + 0);

    hipFuncSetAttribute((const void*)gemm256<4, 3, 0>, hipFuncAttributeMaxDynamicSharedMemorySize, SMEM);
    hipFuncSetAttribute((const void*)gemm256<3, 1, 0>, hipFuncAttributeMaxDynamicSharedMemorySize, SMEM);
    hipFuncSetAttribute((const void*)gemm256<2, 4, 1>, hipFuncAttributeMaxDynamicSharedMemorySize, SMEM);

    // 1) merged prep (src convert + 6 weight transposes + bias concat)
    prep<<<dim3(16384 + 3072 + 6), 256, 0, stream>>>(
        src, src16, Wq, Wk, Wv, Wo, W1, W2, wqkv, wot, w1t, w2t, bq, bk, bv, bqkv);

    // 2) fused QKV GEMM (N=1536, NT=3 over bx -> 256 blocks; elu+1 on q,k segments)
    gemm256<4, 3, 0><<<dim3(2 * 128), 512, SMEM, stream>>>(src16, wqkv, bqkv, nullptr, qm, M, 1536, E, 2);

    // 3) kv / ksum reduction
    kv_partial<<<dim3(16, 32), 256, 0, stream>>>(km, v, kvp, ksump, S);
    kv_reduce<<<dim3((32 * 4096 + 32 * 64 + 255) / 256), 256, 0, stream>>>(kvp, ksump, kvt, ksum);

    // 4) attention combine (MFMA)
    attn_mfma<<<dim3(4, M / 128), 256, 0, stream>>>(qm, kvt, ksum, attnE, S);

    // 5) output proj + bf16 residual, then LN -> x16
    gemm256<3, 1, 0><<<dim3(2 * 128), 512, SMEM, stream>>>(attnE, wot, bo, src16, y16, M, E, E, 2);
    ln_bf16<0><<<dim3(M / 4), 256, 0, stream>>>(y16, g1, be1, x16, M);

    // 6) FFN: W1 (NT=4 over by -> 8 x 32 = 256 blocks, A streamed once), W2 (NT=1)
    gemm256<2, 4, 1><<<dim3(8 * 32), 512, SMEM, stream>>>(x16, w1t, b1, nullptr, hbuf, M, F, E, 8);
    gemm256<3, 1, 0><<<dim3(2 * 128), 512, SMEM, stream>>>(hbuf, w2t, b2, x16, z16, M, E, F, 2);
    ln_bf16<1><<<dim3(M / 4), 256, 0, stream>>>(z16, g2, be2, (float*)d_out, M);
}